// Round 4
// baseline (939.270 us; speedup 1.0000x reference)
//
#include <hip/hip_runtime.h>
#include <hip/hip_bf16.h>
#include <cstdint>
#include <cstdio>

#define NUM_T   8192
#define HDIM    1024
#define IDIM    4096
#define NEXP    8

#define ALGN    256                 // expert group alignment (= fc tile M)
#define RB_FC   72                  // ceil((16384 + 8*255)/256)
#define RB_PJ   144                 // same rows in 128-tiles
#define MAXROWS (RB_FC * 256)       // 18432 padded pair-rows

#define FC_NT   (HDIM / 64)         // 16 K-tiles
#define FC_NI   (FC_NT / 2)         // 8 iterations
#define PJ_NT   (IDIM / 64)         // 64 K-tiles
#define PJ_NI   (PJ_NT / 2)         // 32 iterations

typedef __attribute__((ext_vector_type(8))) short short8;
typedef __attribute__((ext_vector_type(4))) float f32x4;

__device__ __forceinline__ unsigned short f32_to_bf16(float f) {
  uint32_t u = __float_as_uint(f);
  u += 0x7fffu + ((u >> 16) & 1u);   // RNE; inputs are finite
  return (unsigned short)(u >> 16);
}
__device__ __forceinline__ float bf16_to_f32(unsigned short u) {
  return __uint_as_float(((uint32_t)u) << 16);
}
__device__ __forceinline__ uint32_t lds_addr(void* p) {
  return (uint32_t)(uintptr_t)(__attribute__((address_space(3))) void*)p;
}
// bijective XCD swizzle: launch-order bid -> logical wgid, 8 contiguous chunks
__device__ __forceinline__ int xcd_swz(int bid, int nwg) {
  const int q = nwg >> 3, r = nwg & 7;
  const int x = bid & 7, i = bid >> 3;
  return (x < r ? x * (q + 1) : r * (q + 1) + (x - r) * q) + i;
}

#define GL16(srcp, ldsoff) __builtin_amdgcn_global_load_lds( \
    (const __attribute__((address_space(1))) void*)(srcp), \
    (__attribute__((address_space(3))) void*)(Lb + (ldsoff)), 16, 0, 0)

// asm ds_read_b128: opaque to alias analysis -> compiler inserts no waitcnt;
// WE own the waits (lgkmcnt(0) after each barrier, counted vmcnt for stages).
#define DSR(dst, a32) asm volatile("ds_read_b128 %0, %1" : "=v"(dst) : "v"(a32))

// phase fences as volatile asm ("memory"): volatile-asm program order pins
// DSR / GL16 / waitcnt placement. sched_barrier(0) per rule #18.
#define PHASE_SYNC() do { \
    asm volatile("s_barrier\n\ts_waitcnt lgkmcnt(0)" ::: "memory"); \
    __builtin_amdgcn_sched_barrier(0); } while (0)
#define PHASE_END() asm volatile("s_barrier" ::: "memory")
#define VMW(n) asm volatile("s_waitcnt vmcnt(" #n ")" ::: "memory")

// ---------------- fp32 -> bf16 bulk convert ----------------
__global__ void cvt_kernel(const float* __restrict__ in, unsigned short* __restrict__ out, int n4) {
  int i = blockIdx.x * blockDim.x + threadIdx.x;
  const int stride = gridDim.x * blockDim.x;
  for (; i < n4; i += stride) {
    const float4 v = ((const float4*)in)[i];
    ushort4 o;
    o.x = f32_to_bf16(v.x); o.y = f32_to_bf16(v.y);
    o.z = f32_to_bf16(v.z); o.w = f32_to_bf16(v.w);
    ((ushort4*)out)[i] = o;
  }
}

// ---------------- router ----------------
__global__ void router_kernel(const float* __restrict__ x, const float* __restrict__ wg,
                              float* __restrict__ logits, int* __restrict__ tki,
                              float* __restrict__ tkg, int* __restrict__ counts) {
  const int t = blockIdx.x * 4 + (threadIdx.x >> 6);   // one wave per token
  const int lane = threadIdx.x & 63;
  const float* xr = x + (size_t)t * HDIM;
  float acc[NEXP];
#pragma unroll
  for (int e = 0; e < NEXP; ++e) acc[e] = 0.f;
  for (int h = lane; h < HDIM; h += 64) {
    const float xv = xr[h];
#pragma unroll
    for (int e = 0; e < NEXP; ++e) acc[e] += xv * wg[e * HDIM + h];
  }
#pragma unroll
  for (int e = 0; e < NEXP; ++e) {
#pragma unroll
    for (int s = 32; s > 0; s >>= 1) acc[e] += __shfl_xor(acc[e], s, 64);
  }
  if (lane == 0) {
    float v0 = -1e30f, v1 = -1e30f; int i0 = 0, i1 = 0;
#pragma unroll
    for (int e = 0; e < NEXP; ++e) {
      const float v = acc[e];
      logits[(size_t)t * NEXP + e] = v;
      if (v > v0)      { v1 = v0; i1 = i0; v0 = v; i0 = e; }
      else if (v > v1) { v1 = v; i1 = e; }
    }
    const float g0 = 1.f / (1.f + expf(v1 - v0));  // softmax over top-2
    tki[t * 2] = i0; tki[t * 2 + 1] = i1;
    tkg[t * 2] = g0; tkg[t * 2 + 1] = 1.f - g0;
    atomicAdd(&counts[i0], 1);
    atomicAdd(&counts[i1], 1);
  }
}

__global__ void offsets_kernel(const int* __restrict__ counts, int* __restrict__ off) {
  if (threadIdx.x == 0 && blockIdx.x == 0) {
    int o = 0; off[0] = 0;
    for (int e = 0; e < NEXP; ++e) { o += (counts[e] + ALGN - 1) & ~(ALGN - 1); off[e + 1] = o; }
  }
}

__global__ void scatter_kernel(const int* __restrict__ tki, const float* __restrict__ tkg,
                               const int* __restrict__ off, int* __restrict__ fill,
                               int* __restrict__ ptok, float* __restrict__ pgate,
                               int* __restrict__ inv) {
  const int t = blockIdx.x * 256 + threadIdx.x;
  if (t >= NUM_T) return;
#pragma unroll
  for (int k = 0; k < 2; ++k) {
    const int e = tki[t * 2 + k];
    const int pos = off[e] + atomicAdd(&fill[e], 1);
    ptok[pos] = t;
    pgate[pos] = tkg[t * 2 + k];
    inv[t * 2 + k] = pos;
  }
}

// =====================================================================
// fc GEMM: act = gelu(X[perm] @ Wfc[e]^T), 256x256 tile, BK=64, 8 waves
// 8-phase schedule, 2 K-tiles/iter, counted vmcnt(6) @ P4/P8,
// asm ds_read_b128 (no compiler waitcnt), asm s_barrier phases.
// LDS [buf][A0,A1,B0,B1][128x64] bf16 = 128 KiB. XOR chunk swizzle.
// =====================================================================
__launch_bounds__(512, 2)
__global__ void fc_gemm(const unsigned short* __restrict__ xb,
                        const unsigned short* __restrict__ wfcb,
                        const int* __restrict__ ptok,
                        const int* __restrict__ off,
                        unsigned short* __restrict__ act) {
  const int nwg = (IDIM / 256) * RB_FC;
  const int wgid = xcd_swz(blockIdx.x, nwg);
  const int row0 = (wgid / (IDIM / 256)) * 256;
  const int icol0 = (wgid % (IDIM / 256)) * 256;
  if (row0 >= off[8]) return;
  int e = 0;
  while (row0 >= off[e + 1]) ++e;

  __shared__ __align__(16) unsigned short L[2][2][2][128 * 64];
  __shared__ int s_tok[256];
  char* Lb = (char*)&L[0][0][0][0];

  const int tid = threadIdx.x;
  if (tid < 256) s_tok[tid] = ptok[row0 + tid];
  __syncthreads();

  // stage sources: load id = ld*512+tid -> row r, pre-swizzled chunk c
  const int r0 = tid >> 3, r1 = (512 + tid) >> 3;
  const int c0 = (((tid) & 7) ^ (r0 & 7)) * 8, c1 = (((512 + tid) & 7) ^ (r1 & 7)) * 8;
  const unsigned short* sA[2][2];
  const unsigned short* sB[2][2];
  sA[0][0] = xb + (size_t)s_tok[r0] * HDIM + c0;
  sA[0][1] = xb + (size_t)s_tok[r1] * HDIM + c1;
  sA[1][0] = xb + (size_t)s_tok[128 + r0] * HDIM + c0;
  sA[1][1] = xb + (size_t)s_tok[128 + r1] * HDIM + c1;
  const size_t wb = (size_t)e * IDIM + icol0;
  sB[0][0] = wfcb + (wb + r0) * HDIM + c0;
  sB[0][1] = wfcb + (wb + r1) * HDIM + c1;
  sB[1][0] = wfcb + (wb + 128 + r0) * HDIM + c0;
  sB[1][1] = wfcb + (wb + 128 + r1) * HDIM + c1;
  const int dst0 = tid * 16, dst1 = (512 + tid) * 16;

#define FC_STAGE_A(bufi, h, tt) do { \
    GL16(sA[h][0] + (tt) * 64, ((bufi) * 4 + (h)) * 16384 + dst0); \
    GL16(sA[h][1] + (tt) * 64, ((bufi) * 4 + (h)) * 16384 + dst1); } while (0)
#define FC_STAGE_B(bufi, h, tt) do { \
    GL16(sB[h][0] + (tt) * 64, ((bufi) * 4 + 2 + (h)) * 16384 + dst0); \
    GL16(sB[h][1] + (tt) * 64, ((bufi) * 4 + 2 + (h)) * 16384 + dst1); } while (0)

  const int lane = tid & 63;
  const int wid = tid >> 6;
  const int wr = wid >> 2;        // 0..1: 128 rows
  const int wc = wid & 3;         // 0..3: 64 cols

  // ds_read byte offsets inside a 16KB unit (row*128 + swizzled chunk*16)
  int offA[8], offB[4];
#pragma unroll
  for (int m = 0; m < 8; ++m) {
    const int lr = m * 16 + (lane & 15);
    offA[m] = lr * 128 + (((lane >> 4) ^ (lr & 7)) * 16);
  }
#pragma unroll
  for (int n = 0; n < 4; ++n) {
    const int lr = (wc & 1) * 64 + n * 16 + (lane & 15);
    offB[n] = lr * 128 + (((lane >> 4) ^ (lr & 7)) * 16);
  }
  const uint32_t LBu = lds_addr(Lb);
  const uint32_t aBs[2] = { LBu + (uint32_t)(0 * 4 + wr) * 16384u,
                            LBu + (uint32_t)(1 * 4 + wr) * 16384u };
  const uint32_t bBs[2] = { LBu + (uint32_t)(0 * 4 + 2 + (wc >> 1)) * 16384u,
                            LBu + (uint32_t)(1 * 4 + 2 + (wc >> 1)) * 16384u };

  f32x4 acc[8][4];
#pragma unroll
  for (int m = 0; m < 8; ++m)
#pragma unroll
    for (int n = 0; n < 4; ++n) acc[m][n] = (f32x4){0.f, 0.f, 0.f, 0.f};
  short8 a[4][2], b[2][2][2];

#define FC_LOADA(bufi, mh) do { _Pragma("unroll") \
    for (int mi = 0; mi < 4; ++mi) { \
      DSR(a[mi][0], aBs[bufi] + (uint32_t)offA[(mh) * 4 + mi]); \
      DSR(a[mi][1], aBs[bufi] + (uint32_t)(offA[(mh) * 4 + mi] ^ 64)); } } while (0)
#define FC_LOADB(bufi, nh) do { _Pragma("unroll") \
    for (int ni = 0; ni < 2; ++ni) { \
      DSR(b[nh][ni][0], bBs[bufi] + (uint32_t)offB[(nh) * 2 + ni]); \
      DSR(b[nh][ni][1], bBs[bufi] + (uint32_t)(offB[(nh) * 2 + ni] ^ 64)); } } while (0)
#define FC_MFMA(mh, nh) do { __builtin_amdgcn_s_setprio(1); _Pragma("unroll") \
    for (int mi = 0; mi < 4; ++mi) { _Pragma("unroll") \
      for (int ni = 0; ni < 2; ++ni) { \
        acc[(mh)*4+mi][(nh)*2+ni] = __builtin_amdgcn_mfma_f32_16x16x32_bf16(a[mi][0], b[nh][ni][0], acc[(mh)*4+mi][(nh)*2+ni], 0, 0, 0); \
        acc[(mh)*4+mi][(nh)*2+ni] = __builtin_amdgcn_mfma_f32_16x16x32_bf16(a[mi][1], b[nh][ni][1], acc[(mh)*4+mi][(nh)*2+ni], 0, 0, 0); } } \
    __builtin_amdgcn_s_setprio(0); } while (0)

  // prologue: tile0 fully (first 8 loads) + tile1 {A0,B0,B1} (last 6);
  // vmcnt(6) -> all of buf0 landed.
  FC_STAGE_A(0, 0, 0); FC_STAGE_B(0, 0, 0); FC_STAGE_B(0, 1, 0); FC_STAGE_A(0, 1, 0);
  FC_STAGE_A(1, 0, 1); FC_STAGE_B(1, 0, 1); FC_STAGE_B(1, 1, 1);
  VMW(6);
  PHASE_END();

#pragma unroll 1
  for (int i = 0; i < FC_NI; ++i) {
    const int t1 = 2 * i + 1;
    const int T  = (2 * i + 2 < FC_NT) ? 2 * i + 2 : FC_NT - 1;
    const int T1 = (2 * i + 3 < FC_NT) ? 2 * i + 3 : FC_NT - 1;
    // P1: tile t0 (buf0), quadrant (0,0)
    FC_LOADA(0, 0); FC_LOADB(0, 0);
    FC_STAGE_A(1, 1, t1);
    PHASE_SYNC(); FC_MFMA(0, 0); PHASE_END();
    // P2: (0,1)
    FC_LOADB(0, 1);
    PHASE_SYNC(); FC_MFMA(0, 1); PHASE_END();
    // P3: (1,0)
    FC_LOADA(0, 1);
    FC_STAGE_B(0, 0, T);
    PHASE_SYNC(); FC_MFMA(1, 0); PHASE_END();
    // P4: (1,1)
    FC_STAGE_A(0, 0, T); FC_STAGE_B(0, 1, T);
    VMW(6);
    PHASE_SYNC(); FC_MFMA(1, 1); PHASE_END();
    // P5: tile t1 (buf1), (0,0)
    FC_LOADA(1, 0); FC_LOADB(1, 0);
    FC_STAGE_A(0, 1, T);
    PHASE_SYNC(); FC_MFMA(0, 0); PHASE_END();
    // P6: (0,1)
    FC_LOADB(1, 1);
    PHASE_SYNC(); FC_MFMA(0, 1); PHASE_END();
    // P7: (1,0)
    FC_LOADA(1, 1);
    FC_STAGE_B(1, 0, T1);
    PHASE_SYNC(); FC_MFMA(1, 0); PHASE_END();
    // P8: (1,1)
    FC_STAGE_A(1, 0, T1); FC_STAGE_B(1, 1, T1);
    VMW(6);
    PHASE_SYNC(); FC_MFMA(1, 1); PHASE_END();
  }

  // epilogue: exact gelu, bf16 store.  D: row=(lane>>4)*4+r, col=lane&15
#pragma unroll
  for (int m = 0; m < 8; ++m) {
    const int prow = row0 + wr * 128 + m * 16 + (lane >> 4) * 4;
#pragma unroll
    for (int n = 0; n < 4; ++n) {
      const int col = icol0 + wc * 64 + n * 16 + (lane & 15);
#pragma unroll
      for (int r = 0; r < 4; ++r) {
        const float v = acc[m][n][r];
        const float g = 0.5f * v * (1.0f + erff(v * 0.70710678118654752f));
        act[(size_t)(prow + r) * IDIM + col] = f32_to_bf16(g);
      }
    }
  }
#undef FC_STAGE_A
#undef FC_STAGE_B
#undef FC_LOADA
#undef FC_LOADB
#undef FC_MFMA
}

// =====================================================================
// proj GEMM: pair[row] = gate * (act[row] @ Wproj[e]^T), 128x256 tile,
// BK=64, 8 waves (2Mx4N, wave C = 64x64), 4-phase/iter, vmcnt(2) @ P2/P4.
// Same asm ds_read / asm barrier treatment. LDS 96 KiB.
// =====================================================================
__launch_bounds__(512, 2)
__global__ void proj_gemm(const unsigned short* __restrict__ actb,
                          const unsigned short* __restrict__ wpb,
                          const float* __restrict__ pgate,
                          const int* __restrict__ off,
                          unsigned short* __restrict__ pair) {
  const int nwg = (HDIM / 256) * RB_PJ;
  const int wgid = xcd_swz(blockIdx.x, nwg);
  const int row0 = (wgid / (HDIM / 256)) * 128;
  const int hcol0 = (wgid % (HDIM / 256)) * 256;
  if (row0 >= off[8]) return;
  int e = 0;
  while (row0 >= off[e + 1]) ++e;

  __shared__ __align__(16) unsigned short L[2][3][128 * 64];
  __shared__ float s_g[128];
  char* Lb = (char*)&L[0][0][0];

  const int tid = threadIdx.x;
  if (tid < 128) s_g[tid] = pgate[row0 + tid];

  const int r0 = tid >> 3, r1 = (512 + tid) >> 3;
  const int c0 = (((tid) & 7) ^ (r0 & 7)) * 8, c1 = (((512 + tid) & 7) ^ (r1 & 7)) * 8;
  const unsigned short* sA[2];
  const unsigned short* sB[2][2];
  sA[0] = actb + (size_t)(row0 + r0) * IDIM + c0;
  sA[1] = actb + (size_t)(row0 + r1) * IDIM + c1;
  const size_t wb = (size_t)e * HDIM + hcol0;
  sB[0][0] = wpb + (wb + r0) * IDIM + c0;
  sB[0][1] = wpb + (wb + r1) * IDIM + c1;
  sB[1][0] = wpb + (wb + 128 + r0) * IDIM + c0;
  sB[1][1] = wpb + (wb + 128 + r1) * IDIM + c1;
  const int dst0 = tid * 16, dst1 = (512 + tid) * 16;

#define PJ_STAGE_A(bufi, tt) do { \
    GL16(sA[0] + (tt) * 64, ((bufi) * 3 + 0) * 16384 + dst0); \
    GL16(sA[1] + (tt) * 64, ((bufi) * 3 + 0) * 16384 + dst1); } while (0)
#define PJ_STAGE_B(bufi, h, tt) do { \
    GL16(sB[h][0] + (tt) * 64, ((bufi) * 3 + 1 + (h)) * 16384 + dst0); \
    GL16(sB[h][1] + (tt) * 64, ((bufi) * 3 + 1 + (h)) * 16384 + dst1); } while (0)

  const int lane = tid & 63;
  const int wid = tid >> 6;
  const int wr = wid >> 2;        // 0..1: 64 rows
  const int wc = wid & 3;         // 0..3: 64 cols

  int offA[4], offB[4];
#pragma unroll
  for (int m = 0; m < 4; ++m) {
    const int lr = wr * 64 + m * 16 + (lane & 15);
    offA[m] = lr * 128 + (((lane >> 4) ^ (lr & 7)) * 16);
  }
#pragma unroll
  for (int n = 0; n < 4; ++n) {
    const int lr = (wc & 1) * 64 + n * 16 + (lane & 15);
    offB[n] = lr * 128 + (((lane >> 4) ^ (lr & 7)) * 16);
  }
  const uint32_t LBu = lds_addr(Lb);
  const uint32_t aBs[2] = { LBu, LBu + 3u * 16384u };
  const uint32_t bBs[2] = { LBu + (uint32_t)(1 + (wc >> 1)) * 16384u,
                            LBu + (uint32_t)(4 + (wc >> 1)) * 16384u };

  f32x4 acc[4][4];
#pragma unroll
  for (int m = 0; m < 4; ++m)
#pragma unroll
    for (int n = 0; n < 4; ++n) acc[m][n] = (f32x4){0.f, 0.f, 0.f, 0.f};
  short8 a[4][2], b[2][2][2];

#define PJ_LOADA(bufi) do { _Pragma("unroll") \
    for (int mi = 0; mi < 4; ++mi) { \
      DSR(a[mi][0], aBs[bufi] + (uint32_t)offA[mi]); \
      DSR(a[mi][1], aBs[bufi] + (uint32_t)(offA[mi] ^ 64)); } } while (0)
#define PJ_LOADB(bufi, nh) do { _Pragma("unroll") \
    for (int ni = 0; ni < 2; ++ni) { \
      DSR(b[nh][ni][0], bBs[bufi] + (uint32_t)offB[(nh) * 2 + ni]); \
      DSR(b[nh][ni][1], bBs[bufi] + (uint32_t)(offB[(nh) * 2 + ni] ^ 64)); } } while (0)
#define PJ_MFMA(nh) do { __builtin_amdgcn_s_setprio(1); _Pragma("unroll") \
    for (int mi = 0; mi < 4; ++mi) { _Pragma("unroll") \
      for (int ni = 0; ni < 2; ++ni) { \
        acc[mi][(nh)*2+ni] = __builtin_amdgcn_mfma_f32_16x16x32_bf16(a[mi][0], b[nh][ni][0], acc[mi][(nh)*2+ni], 0, 0, 0); \
        acc[mi][(nh)*2+ni] = __builtin_amdgcn_mfma_f32_16x16x32_bf16(a[mi][1], b[nh][ni][1], acc[mi][(nh)*2+ni], 0, 0, 0); } } \
    __builtin_amdgcn_s_setprio(0); } while (0)

  // prologue: A(0),B0(0),B1(0) (first 6) then A(1); vmcnt(2) -> buf0 landed
  PJ_STAGE_A(0, 0); PJ_STAGE_B(0, 0, 0); PJ_STAGE_B(0, 1, 0); PJ_STAGE_A(1, 1);
  VMW(2);
  PHASE_END();

#pragma unroll 1
  for (int i = 0; i < PJ_NI; ++i) {
    const int t1 = 2 * i + 1;
    const int T  = (2 * i + 2 < PJ_NT) ? 2 * i + 2 : PJ_NT - 1;
    const int T1 = (2 * i + 3 < PJ_NT) ? 2 * i + 3 : PJ_NT - 1;
    // P1: tile t0 (buf0), nh=0
    PJ_LOADA(0); PJ_LOADB(0, 0);
    PJ_STAGE_B(1, 0, t1); PJ_STAGE_B(1, 1, t1);
    PHASE_SYNC(); PJ_MFMA(0); PHASE_END();
    // P2: nh=1
    PJ_LOADB(0, 1);
    PJ_STAGE_A(0, T);
    VMW(2);
    PHASE_SYNC(); PJ_MFMA(1); PHASE_END();
    // P3: tile t1 (buf1), nh=0
    PJ_LOADA(1); PJ_LOADB(1, 0);
    PJ_STAGE_B(0, 0, T); PJ_STAGE_B(0, 1, T);
    PHASE_SYNC(); PJ_MFMA(0); PHASE_END();
    // P4: nh=1
    PJ_LOADB(1, 1);
    PJ_STAGE_A(1, T1);
    VMW(2);
    PHASE_SYNC(); PJ_MFMA(1); PHASE_END();
  }

  // epilogue: scale by gate, bf16 store into pair rows (pads have gate 0)
#pragma unroll
  for (int m = 0; m < 4; ++m) {
    const int lr = wr * 64 + m * 16 + (lane >> 4) * 4;
#pragma unroll
    for (int n = 0; n < 4; ++n) {
      const int col = hcol0 + wc * 64 + n * 16 + (lane & 15);
#pragma unroll
      for (int r = 0; r < 4; ++r) {
        const float g = s_g[lr + r];
        pair[(size_t)(row0 + lr + r) * HDIM + col] = f32_to_bf16(g * acc[m][n][r]);
      }
    }
  }
#undef PJ_STAGE_A
#undef PJ_STAGE_B
#undef PJ_LOADA
#undef PJ_LOADB
#undef PJ_MFMA
}

// ---------------- combine: out[t] = pair[inv[t,0]] + pair[inv[t,1]] ----------------
__global__ void combine_kernel(const unsigned short* __restrict__ pair,
                               const int* __restrict__ inv, float* __restrict__ out) {
  const int gid = blockIdx.x * 256 + threadIdx.x;     // NUM_T*HDIM/8 threads
  const int t = gid >> 7;
  const int c8 = (gid & 127) << 3;
  const short8 v0 = *(const short8*)(pair + (size_t)inv[t * 2] * HDIM + c8);
  const short8 v1 = *(const short8*)(pair + (size_t)inv[t * 2 + 1] * HDIM + c8);
  float o[8];
#pragma unroll
  for (int j = 0; j < 8; ++j)
    o[j] = bf16_to_f32((unsigned short)v0[j]) + bf16_to_f32((unsigned short)v1[j]);
  float* dst = out + (size_t)t * HDIM + c8;
  ((float4*)dst)[0] = (float4){o[0], o[1], o[2], o[3]};
  ((float4*)dst)[1] = (float4){o[4], o[5], o[6], o[7]};
}

extern "C" void kernel_launch(void* const* d_in, const int* in_sizes, int n_in,
                              void* d_out, int out_size, void* d_ws, size_t ws_size,
                              hipStream_t stream) {
  const float* x   = (const float*)d_in[0];
  const float* wg  = (const float*)d_in[1];
  const float* wfc = (const float*)d_in[2];
  const float* wpj = (const float*)d_in[3];
  float* out    = (float*)d_out;
  float* logits = out + (size_t)NUM_T * HDIM;

  char* p = (char*)d_ws;
  auto alloc = [&](size_t bytes) { char* q = p; p += (bytes + 255) & ~size_t(255); return q; };
  unsigned short* xb    = (unsigned short*)alloc((size_t)NUM_T * HDIM * 2);
  unsigned short* wfcb  = (unsigned short*)alloc((size_t)NEXP * IDIM * HDIM * 2);
  unsigned short* wpb   = (unsigned short*)alloc((size_t)NEXP * HDIM * IDIM * 2);
  unsigned short* act   = (unsigned short*)alloc((size_t)MAXROWS * IDIM * 2);
  unsigned short* pair  = (unsigned short*)alloc((size_t)MAXROWS * HDIM * 2);
  int*            ptok  = (int*)alloc((size_t)MAXROWS * 4);
  float*          pgate = (float*)alloc((size_t)MAXROWS * 4);
  int*            tki   = (int*)alloc((size_t)NUM_T * 2 * 4);
  float*          tkg   = (float*)alloc((size_t)NUM_T * 2 * 4);
  int*            inv   = (int*)alloc((size_t)NUM_T * 2 * 4);
  int*            counts= (int*)alloc(64);
  int*            fill  = (int*)alloc(64);
  int*            off   = (int*)alloc(64);
  const size_t need = (size_t)(p - (char*)d_ws);
  if (need > ws_size) {
    fprintf(stderr, "kernel_launch: ws too small: need %zu have %zu\n", need, ws_size);
    hipMemsetAsync(d_out, 0, (size_t)out_size * 4, stream);
    return;
  }

  // zero aux region (pads -> token 0 / gate 0; counts/fill for atomics)
  hipMemsetAsync(ptok, 0, (size_t)(p - (char*)ptok), stream);

  cvt_kernel<<<2048, 256, 0, stream>>>(x,   xb,   NUM_T * HDIM / 4);
  cvt_kernel<<<2048, 256, 0, stream>>>(wfc, wfcb, NEXP * IDIM * HDIM / 4);
  cvt_kernel<<<2048, 256, 0, stream>>>(wpj, wpb,  NEXP * HDIM * IDIM / 4);

  router_kernel<<<NUM_T / 4, 256, 0, stream>>>(x, wg, logits, tki, tkg, counts);
  offsets_kernel<<<1, 64, 0, stream>>>(counts, off);
  scatter_kernel<<<NUM_T / 256, 256, 0, stream>>>(tki, tkg, off, fill, ptok, pgate, inv);

  fc_gemm<<<(IDIM / 256) * RB_FC, 512, 0, stream>>>(xb, wfcb, ptok, off, act);
  proj_gemm<<<(HDIM / 256) * RB_PJ, 512, 0, stream>>>(act, wpb, pgate, off, pair);
  combine_kernel<<<NUM_T * HDIM / 8 / 256, 256, 0, stream>>>(pair, inv, out);
}

// Round 7
// 819.033 us; speedup vs baseline: 1.1468x; 1.1468x over previous
//
#include <hip/hip_runtime.h>
#include <hip/hip_bf16.h>
#include <cstdint>
#include <cstdio>

#define NUM_T   8192
#define HDIM    1024
#define IDIM    4096
#define NEXP    8

#define ALGN    256                 // expert group alignment (= fc tile M)
#define RB_FC   72                  // ceil((16384 + 8*255)/256)
#define RB_PJ   144                 // same rows in 128-tiles
#define MAXROWS (RB_FC * 256)       // 18432 padded pair-rows

#define FC_NT   (HDIM / 64)         // 16 K-tiles
#define FC_NI   (FC_NT / 2)         // 8 iterations
#define PJ_NT   (IDIM / 64)         // 64 K-tiles
#define PJ_NI   (PJ_NT / 2)         // 32 iterations

typedef __attribute__((ext_vector_type(8))) short short8;
typedef __attribute__((ext_vector_type(4))) float f32x4;

__device__ __forceinline__ unsigned short f32_to_bf16(float f) {
  uint32_t u = __float_as_uint(f);
  u += 0x7fffu + ((u >> 16) & 1u);   // RNE; inputs are finite
  return (unsigned short)(u >> 16);
}
__device__ __forceinline__ float bf16_to_f32(unsigned short u) {
  return __uint_as_float(((uint32_t)u) << 16);
}
__device__ __forceinline__ uint32_t lds_addr(void* p) {
  return (uint32_t)(uintptr_t)(__attribute__((address_space(3))) void*)p;
}
// bijective XCD swizzle: launch-order bid -> logical wgid, 8 contiguous chunks
__device__ __forceinline__ int xcd_swz(int bid, int nwg) {
  const int q = nwg >> 3, r = nwg & 7;
  const int x = bid & 7, i = bid >> 3;
  return (x < r ? x * (q + 1) : r * (q + 1) + (x - r) * q) + i;
}

#define GL16(srcp, ldsoff) __builtin_amdgcn_global_load_lds( \
    (const __attribute__((address_space(1))) void*)(srcp), \
    (__attribute__((address_space(3))) void*)(Lb + (ldsoff)), 16, 0, 0)

// asm ds_read_b128 with compile-time offset immediate: opaque to alias
// analysis (no compiler waitcnt); zero per-read address VALU.
#define DSRO(dst, b32, imm) \
  asm volatile("ds_read_b128 %0, %1 offset:" #imm : "=v"(dst) : "v"(b32))

// phase fences as volatile asm ("memory"): volatile-asm program order pins
// DSRO / GL16 / waitcnt placement. sched_barrier(0) per rule #18.
#define PHASE_SYNC() do { \
    asm volatile("s_barrier\n\ts_waitcnt lgkmcnt(0)" ::: "memory"); \
    __builtin_amdgcn_sched_barrier(0); } while (0)
#define PHASE_END() asm volatile("s_barrier" ::: "memory")
#define VMW(n) asm volatile("s_waitcnt vmcnt(" #n ")" ::: "memory")

// ---------------- fp32 -> bf16 bulk convert ----------------
__global__ void cvt_kernel(const float* __restrict__ in, unsigned short* __restrict__ out, int n4) {
  int i = blockIdx.x * blockDim.x + threadIdx.x;
  const int stride = gridDim.x * blockDim.x;
  for (; i < n4; i += stride) {
    const float4 v = ((const float4*)in)[i];
    ushort4 o;
    o.x = f32_to_bf16(v.x); o.y = f32_to_bf16(v.y);
    o.z = f32_to_bf16(v.z); o.w = f32_to_bf16(v.w);
    ((ushort4*)out)[i] = o;
  }
}

// ---------------- router ----------------
__global__ void router_kernel(const float* __restrict__ x, const float* __restrict__ wg,
                              float* __restrict__ logits, int* __restrict__ tki,
                              float* __restrict__ tkg, int* __restrict__ counts) {
  const int t = blockIdx.x * 4 + (threadIdx.x >> 6);   // one wave per token
  const int lane = threadIdx.x & 63;
  const float* xr = x + (size_t)t * HDIM;
  float acc[NEXP];
#pragma unroll
  for (int e = 0; e < NEXP; ++e) acc[e] = 0.f;
  for (int h = lane; h < HDIM; h += 64) {
    const float xv = xr[h];
#pragma unroll
    for (int e = 0; e < NEXP; ++e) acc[e] += xv * wg[e * HDIM + h];
  }
#pragma unroll
  for (int e = 0; e < NEXP; ++e) {
#pragma unroll
    for (int s = 32; s > 0; s >>= 1) acc[e] += __shfl_xor(acc[e], s, 64);
  }
  if (lane == 0) {
    float v0 = -1e30f, v1 = -1e30f; int i0 = 0, i1 = 0;
#pragma unroll
    for (int e = 0; e < NEXP; ++e) {
      const float v = acc[e];
      logits[(size_t)t * NEXP + e] = v;
      if (v > v0)      { v1 = v0; i1 = i0; v0 = v; i0 = e; }
      else if (v > v1) { v1 = v; i1 = e; }
    }
    const float g0 = 1.f / (1.f + expf(v1 - v0));  // softmax over top-2
    tki[t * 2] = i0; tki[t * 2 + 1] = i1;
    tkg[t * 2] = g0; tkg[t * 2 + 1] = 1.f - g0;
    atomicAdd(&counts[i0], 1);
    atomicAdd(&counts[i1], 1);
  }
}

__global__ void offsets_kernel(const int* __restrict__ counts, int* __restrict__ off) {
  if (threadIdx.x == 0 && blockIdx.x == 0) {
    int o = 0; off[0] = 0;
    for (int e = 0; e < NEXP; ++e) { o += (counts[e] + ALGN - 1) & ~(ALGN - 1); off[e + 1] = o; }
  }
}

__global__ void scatter_kernel(const int* __restrict__ tki, const float* __restrict__ tkg,
                               const int* __restrict__ off, int* __restrict__ fill,
                               int* __restrict__ ptok, float* __restrict__ pgate,
                               int* __restrict__ inv) {
  const int t = blockIdx.x * 256 + threadIdx.x;
  if (t >= NUM_T) return;
#pragma unroll
  for (int k = 0; k < 2; ++k) {
    const int e = tki[t * 2 + k];
    const int pos = off[e] + atomicAdd(&fill[e], 1);
    ptok[pos] = t;
    pgate[pos] = tkg[t * 2 + k];
    inv[t * 2 + k] = pos;
  }
}

// =====================================================================
// fc GEMM: act = gelu(X[perm] @ Wfc[e]^T), 256x256 tile, BK=64, 8 waves
// 8-phase schedule, 2 K-tiles/iter, counted vmcnt(4) @ P4/P8,
// asm ds_read_b128 w/ offset imm, asm s_barrier phases.
// LDS [buf][A0,A1,B0,B1][128x64] bf16 = 128 KiB. XOR chunk swizzle.
// STAGE SCHEDULE (race-audited: every unit's stage is >=1 END-barrier
// after its last ds_read, incl. the shared-b reload reads):
//   P1: buf1-A1,B1(t1)   [last reads: prev P7 / prev P8]
//   P4: buf0-A0,B0(T)    [last reads: P3 / P3]
//   P5: buf0-A1,B1(T)    [last reads: P3 / P4]
//   P8: buf1-A0,B0(T1)   [last reads: P7 / P7]
// vmcnt(4)@P4 retires {P8_prev, P1} batches -> buf1 complete before P5;
// vmcnt(4)@P8 retires {P4, P5} batches -> buf0 complete before next P1.
// VMW precedes the barrier => cross-wave safe.
// =====================================================================
__launch_bounds__(512, 2)
__global__ void fc_gemm(const unsigned short* __restrict__ xb,
                        const unsigned short* __restrict__ wfcb,
                        const int* __restrict__ ptok,
                        const int* __restrict__ off,
                        unsigned short* __restrict__ act) {
  const int nwg = (IDIM / 256) * RB_FC;
  const int wgid = xcd_swz(blockIdx.x, nwg);
  const int row0 = (wgid / (IDIM / 256)) * 256;
  const int icol0 = (wgid % (IDIM / 256)) * 256;
  if (row0 >= off[8]) return;
  int e = 0;
  while (row0 >= off[e + 1]) ++e;

  __shared__ __align__(16) unsigned short L[2][2][2][128 * 64];
  __shared__ int s_tok[256];
  char* Lb = (char*)&L[0][0][0][0];

  const int tid = threadIdx.x;
  if (tid < 256) s_tok[tid] = ptok[row0 + tid];
  __syncthreads();

  // stage sources: load id = ld*512+tid -> row r = id>>3, pre-swizzled chunk
  const int r0 = tid >> 3, r1 = 64 + r0;
  const int c0 = ((tid & 7) ^ (r0 & 7)) * 8;     // r1&7 == r0&7 -> same chunk
  const unsigned short* sA00 = xb + (size_t)s_tok[r0] * HDIM + c0;
  const unsigned short* sA01 = xb + (size_t)s_tok[r1] * HDIM + c0;
  const unsigned short* sA10 = xb + (size_t)s_tok[128 + r0] * HDIM + c0;
  const unsigned short* sA11 = xb + (size_t)s_tok[128 + r1] * HDIM + c0;
  const size_t wb = (size_t)e * IDIM + icol0;
  const unsigned short* sB0 = wfcb + (wb + r0) * HDIM + c0;        // +64*HDIM for 2nd
  const unsigned short* sB1 = wfcb + (wb + 128 + r0) * HDIM + c0;
  const int dst0 = tid * 16;                     // 2nd load: +8192

#define FC_STAGE_A(bufi, h, tt) do { \
    GL16(((h) ? sA10 : sA00) + (tt) * 64, ((bufi) * 4 + (h)) * 16384 + dst0); \
    GL16(((h) ? sA11 : sA01) + (tt) * 64, ((bufi) * 4 + (h)) * 16384 + dst0 + 8192); } while (0)
#define FC_STAGE_B(bufi, h, tt) do { \
    GL16(((h) ? sB1 : sB0) + (tt) * 64, ((bufi) * 4 + 2 + (h)) * 16384 + dst0); \
    GL16(((h) ? sB1 : sB0) + 64 * HDIM + (tt) * 64, ((bufi) * 4 + 2 + (h)) * 16384 + dst0 + 8192); } while (0)

  const int lane = tid & 63;
  const int wid = tid >> 6;
  const int wr = wid >> 2;        // 0..1: 128 rows
  const int wc = wid & 3;         // 0..3: 64 cols

  // LDS read bases: unit + (lane&15)*128 + swz*16; row steps are imm offsets.
  // swz = (lane>>4)^(lane&7) (row&7 == lane&7 for all fragment rows).
  const uint32_t LBu = lds_addr(Lb);
  const uint32_t rb = (uint32_t)((lane & 15) * 128 + (((lane >> 4) ^ (lane & 7)) * 16));
  const uint32_t aA[2]  = { LBu + (uint32_t)(0 * 4 + wr) * 16384u + rb,
                            LBu + (uint32_t)(1 * 4 + wr) * 16384u + rb };
  const uint32_t aAx[2] = { aA[0] ^ 64u, aA[1] ^ 64u };
  const uint32_t bbase = rb + (uint32_t)((wc & 1) * 8192);
  const uint32_t bB[2]  = { LBu + (uint32_t)(0 * 4 + 2 + (wc >> 1)) * 16384u + bbase,
                            LBu + (uint32_t)(1 * 4 + 2 + (wc >> 1)) * 16384u + bbase };
  const uint32_t bBx[2] = { bB[0] ^ 64u, bB[1] ^ 64u };

  f32x4 acc[8][4];
#pragma unroll
  for (int m = 0; m < 8; ++m)
#pragma unroll
    for (int n = 0; n < 4; ++n) acc[m][n] = (f32x4){0.f, 0.f, 0.f, 0.f};
  short8 a[4][2], b[2][2];        // b shared across nh groups (time-mux)

#define FC_LOADA0(B) do { \
    DSRO(a[0][0], aA[B], 0);     DSRO(a[0][1], aAx[B], 0); \
    DSRO(a[1][0], aA[B], 2048);  DSRO(a[1][1], aAx[B], 2048); \
    DSRO(a[2][0], aA[B], 4096);  DSRO(a[2][1], aAx[B], 4096); \
    DSRO(a[3][0], aA[B], 6144);  DSRO(a[3][1], aAx[B], 6144); } while (0)
#define FC_LOADA1(B) do { \
    DSRO(a[0][0], aA[B], 8192);  DSRO(a[0][1], aAx[B], 8192); \
    DSRO(a[1][0], aA[B], 10240); DSRO(a[1][1], aAx[B], 10240); \
    DSRO(a[2][0], aA[B], 12288); DSRO(a[2][1], aAx[B], 12288); \
    DSRO(a[3][0], aA[B], 14336); DSRO(a[3][1], aAx[B], 14336); } while (0)
#define FC_LOADB0(B) do { \
    DSRO(b[0][0], bB[B], 0);     DSRO(b[0][1], bBx[B], 0); \
    DSRO(b[1][0], bB[B], 2048);  DSRO(b[1][1], bBx[B], 2048); } while (0)
#define FC_LOADB1(B) do { \
    DSRO(b[0][0], bB[B], 4096);  DSRO(b[0][1], bBx[B], 4096); \
    DSRO(b[1][0], bB[B], 6144);  DSRO(b[1][1], bBx[B], 6144); } while (0)
#define FC_MFMA(mh, nh) do { __builtin_amdgcn_s_setprio(1); _Pragma("unroll") \
    for (int mi = 0; mi < 4; ++mi) { _Pragma("unroll") \
      for (int ni = 0; ni < 2; ++ni) { \
        acc[(mh)*4+mi][(nh)*2+ni] = __builtin_amdgcn_mfma_f32_16x16x32_bf16(a[mi][0], b[ni][0], acc[(mh)*4+mi][(nh)*2+ni], 0, 0, 0); \
        acc[(mh)*4+mi][(nh)*2+ni] = __builtin_amdgcn_mfma_f32_16x16x32_bf16(a[mi][1], b[ni][1], acc[(mh)*4+mi][(nh)*2+ni], 0, 0, 0); } } \
    __builtin_amdgcn_s_setprio(0); } while (0)

  // prologue: buf0 tile0 fully (8 loads) + buf1 tile1 {A0,B0} (4 loads);
  // vmcnt(4) -> buf0 fully landed; barrier fences cross-wave.
  FC_STAGE_A(0, 0, 0); FC_STAGE_B(0, 0, 0); FC_STAGE_A(0, 1, 0); FC_STAGE_B(0, 1, 0);
  FC_STAGE_A(1, 0, 1); FC_STAGE_B(1, 0, 1);
  VMW(4);
  PHASE_END();

#pragma unroll 1
  for (int i = 0; i < FC_NI; ++i) {
    const int t1 = 2 * i + 1;
    const int T  = (2 * i + 2 < FC_NT) ? 2 * i + 2 : FC_NT - 1;
    const int T1 = (2 * i + 3 < FC_NT) ? 2 * i + 3 : FC_NT - 1;
    // P1: tile t0 (buf0), quadrant (0,0); stage buf1-A1,B1(t1)
    FC_LOADA0(0); FC_LOADB0(0);
    FC_STAGE_A(1, 1, t1); FC_STAGE_B(1, 1, t1);
    PHASE_SYNC(); FC_MFMA(0, 0); PHASE_END();
    // P2: (0,1)
    FC_LOADB1(0);
    PHASE_SYNC(); FC_MFMA(0, 1); PHASE_END();
    // P3: (1,0)  (b reload nh=0)
    FC_LOADA1(0); FC_LOADB0(0);
    PHASE_SYNC(); FC_MFMA(1, 0); PHASE_END();
    // P4: (1,1); stage buf0-A0,B0(T); vmcnt(4) retires {P8_prev,P1}
    FC_LOADB1(0);
    FC_STAGE_A(0, 0, T); FC_STAGE_B(0, 0, T);
    VMW(4);
    PHASE_SYNC(); FC_MFMA(1, 1); PHASE_END();
    // P5: tile t1 (buf1), (0,0); stage buf0-A1,B1(T)
    FC_LOADA0(1); FC_LOADB0(1);
    FC_STAGE_A(0, 1, T); FC_STAGE_B(0, 1, T);
    PHASE_SYNC(); FC_MFMA(0, 0); PHASE_END();
    // P6: (0,1)
    FC_LOADB1(1);
    PHASE_SYNC(); FC_MFMA(0, 1); PHASE_END();
    // P7: (1,0)
    FC_LOADA1(1); FC_LOADB0(1);
    PHASE_SYNC(); FC_MFMA(1, 0); PHASE_END();
    // P8: (1,1); stage buf1-A0,B0(T1); vmcnt(4) retires {P4,P5}
    FC_LOADB1(1);
    FC_STAGE_A(1, 0, T1); FC_STAGE_B(1, 0, T1);
    VMW(4);
    PHASE_SYNC(); FC_MFMA(1, 1); PHASE_END();
  }

  // epilogue: exact gelu, bf16 store.  D: row=(lane>>4)*4+r, col=lane&15
#pragma unroll
  for (int m = 0; m < 8; ++m) {
    const int prow = row0 + wr * 128 + m * 16 + (lane >> 4) * 4;
#pragma unroll
    for (int n = 0; n < 4; ++n) {
      const int col = icol0 + wc * 64 + n * 16 + (lane & 15);
#pragma unroll
      for (int r = 0; r < 4; ++r) {
        const float v = acc[m][n][r];
        const float g = 0.5f * v * (1.0f + erff(v * 0.70710678118654752f));
        act[(size_t)(prow + r) * IDIM + col] = f32_to_bf16(g);
      }
    }
  }
#undef FC_STAGE_A
#undef FC_STAGE_B
#undef FC_LOADA0
#undef FC_LOADA1
#undef FC_LOADB0
#undef FC_LOADB1
#undef FC_MFMA
}

// =====================================================================
// proj GEMM: pair[row] = gate * (act[row] @ Wproj[e]^T), 128x256 tile,
// BK=64, 8 waves (2Mx4N, wave C = 64x64), 4-phase/iter, vmcnt(2) @ P2/P4.
// Stage/read audit (shared-b reloads included): no unit is staged in the
// same phase as any read of it; every stage >=1 END-barrier after last read.
// =====================================================================
__launch_bounds__(512, 2)
__global__ void proj_gemm(const unsigned short* __restrict__ actb,
                          const unsigned short* __restrict__ wpb,
                          const float* __restrict__ pgate,
                          const int* __restrict__ off,
                          unsigned short* __restrict__ pair) {
  const int nwg = (HDIM / 256) * RB_PJ;
  const int wgid = xcd_swz(blockIdx.x, nwg);
  const int row0 = (wgid / (HDIM / 256)) * 128;
  const int hcol0 = (wgid % (HDIM / 256)) * 256;
  if (row0 >= off[8]) return;
  int e = 0;
  while (row0 >= off[e + 1]) ++e;

  __shared__ __align__(16) unsigned short L[2][3][128 * 64];
  __shared__ float s_g[128];
  char* Lb = (char*)&L[0][0][0];

  const int tid = threadIdx.x;
  if (tid < 128) s_g[tid] = pgate[row0 + tid];

  const int r0 = tid >> 3;
  const int c0 = ((tid & 7) ^ (r0 & 7)) * 8;     // r1 = r0+64: same chunk
  const unsigned short* sA0 = actb + (size_t)(row0 + r0) * IDIM + c0;  // +64*IDIM 2nd
  const size_t wb = (size_t)e * HDIM + hcol0;
  const unsigned short* sB0 = wpb + (wb + r0) * IDIM + c0;
  const unsigned short* sB1 = wpb + (wb + 128 + r0) * IDIM + c0;
  const int dst0 = tid * 16;

#define PJ_STAGE_A(bufi, tt) do { \
    GL16(sA0 + (tt) * 64, ((bufi) * 3 + 0) * 16384 + dst0); \
    GL16(sA0 + 64 * IDIM + (tt) * 64, ((bufi) * 3 + 0) * 16384 + dst0 + 8192); } while (0)
#define PJ_STAGE_B(bufi, h, tt) do { \
    GL16(((h) ? sB1 : sB0) + (tt) * 64, ((bufi) * 3 + 1 + (h)) * 16384 + dst0); \
    GL16(((h) ? sB1 : sB0) + 64 * IDIM + (tt) * 64, ((bufi) * 3 + 1 + (h)) * 16384 + dst0 + 8192); } while (0)

  const int lane = tid & 63;
  const int wid = tid >> 6;
  const int wr = wid >> 2;        // 0..1: 64 rows
  const int wc = wid & 3;         // 0..3: 64 cols

  const uint32_t LBu = lds_addr(Lb);
  const uint32_t rb = (uint32_t)((lane & 15) * 128 + (((lane >> 4) ^ (lane & 7)) * 16));
  const uint32_t aA[2]  = { LBu + 0u * 16384u + (uint32_t)(wr * 8192) + rb,
                            LBu + 3u * 16384u + (uint32_t)(wr * 8192) + rb };
  const uint32_t aAx[2] = { aA[0] ^ 64u, aA[1] ^ 64u };
  const uint32_t bbase = rb + (uint32_t)((wc & 1) * 8192);
  const uint32_t bB[2]  = { LBu + (uint32_t)(1 + (wc >> 1)) * 16384u + bbase,
                            LBu + (uint32_t)(4 + (wc >> 1)) * 16384u + bbase };
  const uint32_t bBx[2] = { bB[0] ^ 64u, bB[1] ^ 64u };

  f32x4 acc[4][4];
#pragma unroll
  for (int m = 0; m < 4; ++m)
#pragma unroll
    for (int n = 0; n < 4; ++n) acc[m][n] = (f32x4){0.f, 0.f, 0.f, 0.f};
  short8 a[4][2], b[2][2];

#define PJ_LOADA(B) do { \
    DSRO(a[0][0], aA[B], 0);     DSRO(a[0][1], aAx[B], 0); \
    DSRO(a[1][0], aA[B], 2048);  DSRO(a[1][1], aAx[B], 2048); \
    DSRO(a[2][0], aA[B], 4096);  DSRO(a[2][1], aAx[B], 4096); \
    DSRO(a[3][0], aA[B], 6144);  DSRO(a[3][1], aAx[B], 6144); } while (0)
#define PJ_LOADB0(B) do { \
    DSRO(b[0][0], bB[B], 0);     DSRO(b[0][1], bBx[B], 0); \
    DSRO(b[1][0], bB[B], 2048);  DSRO(b[1][1], bBx[B], 2048); } while (0)
#define PJ_LOADB1(B) do { \
    DSRO(b[0][0], bB[B], 4096);  DSRO(b[0][1], bBx[B], 4096); \
    DSRO(b[1][0], bB[B], 6144);  DSRO(b[1][1], bBx[B], 6144); } while (0)
#define PJ_MFMA(nh) do { __builtin_amdgcn_s_setprio(1); _Pragma("unroll") \
    for (int mi = 0; mi < 4; ++mi) { _Pragma("unroll") \
      for (int ni = 0; ni < 2; ++ni) { \
        acc[mi][(nh)*2+ni] = __builtin_amdgcn_mfma_f32_16x16x32_bf16(a[mi][0], b[ni][0], acc[mi][(nh)*2+ni], 0, 0, 0); \
        acc[mi][(nh)*2+ni] = __builtin_amdgcn_mfma_f32_16x16x32_bf16(a[mi][1], b[ni][1], acc[mi][(nh)*2+ni], 0, 0, 0); } } \
    __builtin_amdgcn_s_setprio(0); } while (0)

  // prologue: A(0),B0(0),B1(0) (first 6) then A(1); vmcnt(2) -> buf0 landed
  PJ_STAGE_A(0, 0); PJ_STAGE_B(0, 0, 0); PJ_STAGE_B(0, 1, 0); PJ_STAGE_A(1, 1);
  VMW(2);
  PHASE_END();

#pragma unroll 1
  for (int i = 0; i < PJ_NI; ++i) {
    const int t1 = 2 * i + 1;
    const int T  = (2 * i + 2 < PJ_NT) ? 2 * i + 2 : PJ_NT - 1;
    const int T1 = (2 * i + 3 < PJ_NT) ? 2 * i + 3 : PJ_NT - 1;
    // P1: tile t0 (buf0), nh=0; stage buf1-B0,B1(t1)
    PJ_LOADA(0); PJ_LOADB0(0);
    PJ_STAGE_B(1, 0, t1); PJ_STAGE_B(1, 1, t1);
    PHASE_SYNC(); PJ_MFMA(0); PHASE_END();
    // P2: nh=1; stage buf0-A(T); vmcnt(2) retires {P4_prev, P1}
    PJ_LOADB1(0);
    PJ_STAGE_A(0, T);
    VMW(2);
    PHASE_SYNC(); PJ_MFMA(1); PHASE_END();
    // P3: tile t1 (buf1), nh=0; stage buf0-B0,B1(T)
    PJ_LOADA(1); PJ_LOADB0(1);
    PJ_STAGE_B(0, 0, T); PJ_STAGE_B(0, 1, T);
    PHASE_SYNC(); PJ_MFMA(0); PHASE_END();
    // P4: nh=1; stage buf1-A(T1); vmcnt(2) retires {P2, P3}
    PJ_LOADB1(1);
    PJ_STAGE_A(1, T1);
    VMW(2);
    PHASE_SYNC(); PJ_MFMA(1); PHASE_END();
  }

  // epilogue: scale by gate, bf16 store into pair rows (pads have gate 0)
#pragma unroll
  for (int m = 0; m < 4; ++m) {
    const int lr = wr * 64 + m * 16 + (lane >> 4) * 4;
#pragma unroll
    for (int n = 0; n < 4; ++n) {
      const int col = hcol0 + wc * 64 + n * 16 + (lane & 15);
#pragma unroll
      for (int r = 0; r < 4; ++r) {
        const float g = s_g[lr + r];
        pair[(size_t)(row0 + lr + r) * HDIM + col] = f32_to_bf16(g * acc[m][n][r]);
      }
    }
  }
#undef PJ_STAGE_A
#undef PJ_STAGE_B
#undef PJ_LOADA
#undef PJ_LOADB0
#undef PJ_LOADB1
#undef PJ_MFMA
}

// ---------------- combine: out[t] = pair[inv[t,0]] + pair[inv[t,1]] ----------------
__global__ void combine_kernel(const unsigned short* __restrict__ pair,
                               const int* __restrict__ inv, float* __restrict__ out) {
  const int gid = blockIdx.x * 256 + threadIdx.x;     // NUM_T*HDIM/8 threads
  const int t = gid >> 7;
  const int c8 = (gid & 127) << 3;
  const short8 v0 = *(const short8*)(pair + (size_t)inv[t * 2] * HDIM + c8);
  const short8 v1 = *(const short8*)(pair + (size_t)inv[t * 2 + 1] * HDIM + c8);
  float o[8];
#pragma unroll
  for (int j = 0; j < 8; ++j)
    o[j] = bf16_to_f32((unsigned short)v0[j]) + bf16_to_f32((unsigned short)v1[j]);
  float* dst = out + (size_t)t * HDIM + c8;
  ((float4*)dst)[0] = (float4){o[0], o[1], o[2], o[3]};
  ((float4*)dst)[1] = (float4){o[4], o[5], o[6], o[7]};
}

extern "C" void kernel_launch(void* const* d_in, const int* in_sizes, int n_in,
                              void* d_out, int out_size, void* d_ws, size_t ws_size,
                              hipStream_t stream) {
  const float* x   = (const float*)d_in[0];
  const float* wg  = (const float*)d_in[1];
  const float* wfc = (const float*)d_in[2];
  const float* wpj = (const float*)d_in[3];
  float* out    = (float*)d_out;
  float* logits = out + (size_t)NUM_T * HDIM;

  char* p = (char*)d_ws;
  auto alloc = [&](size_t bytes) { char* q = p; p += (bytes + 255) & ~size_t(255); return q; };
  unsigned short* xb    = (unsigned short*)alloc((size_t)NUM_T * HDIM * 2);
  unsigned short* wfcb  = (unsigned short*)alloc((size_t)NEXP * IDIM * HDIM * 2);
  unsigned short* wpb   = (unsigned short*)alloc((size_t)NEXP * HDIM * IDIM * 2);
  unsigned short* act   = (unsigned short*)alloc((size_t)MAXROWS * IDIM * 2);
  unsigned short* pair  = (unsigned short*)alloc((size_t)MAXROWS * HDIM * 2);
  int*            ptok  = (int*)alloc((size_t)MAXROWS * 4);
  float*          pgate = (float*)alloc((size_t)MAXROWS * 4);
  int*            tki   = (int*)alloc((size_t)NUM_T * 2 * 4);
  float*          tkg   = (float*)alloc((size_t)NUM_T * 2 * 4);
  int*            inv   = (int*)alloc((size_t)NUM_T * 2 * 4);
  int*            counts= (int*)alloc(64);
  int*            fill  = (int*)alloc(64);
  int*            off   = (int*)alloc(64);
  const size_t need = (size_t)(p - (char*)d_ws);
  if (need > ws_size) {
    fprintf(stderr, "kernel_launch: ws too small: need %zu have %zu\n", need, ws_size);
    hipMemsetAsync(d_out, 0, (size_t)out_size * 4, stream);
    return;
  }

  // zero aux region (pads -> token 0 / gate 0; counts/fill for atomics)
  hipMemsetAsync(ptok, 0, (size_t)(p - (char*)ptok), stream);

  cvt_kernel<<<2048, 256, 0, stream>>>(x,   xb,   NUM_T * HDIM / 4);
  cvt_kernel<<<2048, 256, 0, stream>>>(wfc, wfcb, NEXP * IDIM * HDIM / 4);
  cvt_kernel<<<2048, 256, 0, stream>>>(wpj, wpb,  NEXP * HDIM * IDIM / 4);

  router_kernel<<<NUM_T / 4, 256, 0, stream>>>(x, wg, logits, tki, tkg, counts);
  offsets_kernel<<<1, 64, 0, stream>>>(counts, off);
  scatter_kernel<<<NUM_T / 256, 256, 0, stream>>>(tki, tkg, off, fill, ptok, pgate, inv);

  fc_gemm<<<(IDIM / 256) * RB_FC, 512, 0, stream>>>(xb, wfcb, ptok, off, act);
  proj_gemm<<<(HDIM / 256) * RB_PJ, 512, 0, stream>>>(act, wpb, pgate, off, pair);
  combine_kernel<<<NUM_T * HDIM / 8 / 256, 256, 0, stream>>>(pair, inv, out);
}

// Round 8
// 716.927 us; speedup vs baseline: 1.3101x; 1.1424x over previous
//
#include <hip/hip_runtime.h>
#include <hip/hip_bf16.h>
#include <cstdint>
#include <cstdio>

#define NUM_T   8192
#define HDIM    1024
#define IDIM    4096
#define NEXP    8

#define ALGN    128                 // expert group alignment (= tile M)
#define RB      136                 // ceil((16384 + 8*127)/128)
#define MAXROWS (RB * 128)          // 17408 padded pair-rows

typedef __attribute__((ext_vector_type(8))) short short8;
typedef __attribute__((ext_vector_type(4))) float f32x4;

__device__ __forceinline__ unsigned short f32_to_bf16(float f) {
  uint32_t u = __float_as_uint(f);
  u += 0x7fffu + ((u >> 16) & 1u);   // RNE; inputs are finite
  return (unsigned short)(u >> 16);
}
__device__ __forceinline__ float bf16_to_f32(unsigned short u) {
  return __uint_as_float(((uint32_t)u) << 16);
}
// bijective XCD swizzle: launch-order bid -> logical wgid, 8 contiguous chunks
__device__ __forceinline__ int xcd_swz(int bid, int nwg) {
  const int q = nwg >> 3, r = nwg & 7;
  const int x = bid & 7, i = bid >> 3;
  return (x < r ? x * (q + 1) : r * (q + 1) + (x - r) * q) + i;
}

// ---------------- fp32 -> bf16 bulk convert (weights) ----------------
__global__ void cvt_kernel(const float* __restrict__ in, unsigned short* __restrict__ out, int n4) {
  int i = blockIdx.x * blockDim.x + threadIdx.x;
  const int stride = gridDim.x * blockDim.x;
  for (; i < n4; i += stride) {
    const float4 v = ((const float4*)in)[i];
    ushort4 o;
    o.x = f32_to_bf16(v.x); o.y = f32_to_bf16(v.y);
    o.z = f32_to_bf16(v.z); o.w = f32_to_bf16(v.w);
    ((ushort4*)out)[i] = o;
  }
}

// ---------------- router: logits fp32, top-2 softmax, counts; emits xb ----------------
__global__ void router_kernel(const float* __restrict__ x, const float* __restrict__ wg,
                              float* __restrict__ logits, int* __restrict__ tki,
                              float* __restrict__ tkg, int* __restrict__ counts,
                              unsigned short* __restrict__ xb) {
  const int t = blockIdx.x * 4 + (threadIdx.x >> 6);   // one wave per token
  const int lane = threadIdx.x & 63;
  const float* xr = x + (size_t)t * HDIM;
  unsigned short* xbr = xb + (size_t)t * HDIM;
  float acc[NEXP];
#pragma unroll
  for (int e = 0; e < NEXP; ++e) acc[e] = 0.f;
  for (int h = lane; h < HDIM; h += 64) {
    const float xv = xr[h];
    xbr[h] = f32_to_bf16(xv);          // fused x -> bf16
#pragma unroll
    for (int e = 0; e < NEXP; ++e) acc[e] += xv * wg[e * HDIM + h];
  }
#pragma unroll
  for (int e = 0; e < NEXP; ++e) {
#pragma unroll
    for (int s = 32; s > 0; s >>= 1) acc[e] += __shfl_xor(acc[e], s, 64);
  }
  if (lane == 0) {
    float v0 = -1e30f, v1 = -1e30f; int i0 = 0, i1 = 0;
#pragma unroll
    for (int e = 0; e < NEXP; ++e) {
      const float v = acc[e];
      logits[(size_t)t * NEXP + e] = v;
      if (v > v0)      { v1 = v0; i1 = i0; v0 = v; i0 = e; }
      else if (v > v1) { v1 = v; i1 = e; }
    }
    const float g0 = 1.f / (1.f + expf(v1 - v0));  // softmax over top-2
    tki[t * 2] = i0; tki[t * 2 + 1] = i1;
    tkg[t * 2] = g0; tkg[t * 2 + 1] = 1.f - g0;
    atomicAdd(&counts[i0], 1);
    atomicAdd(&counts[i1], 1);
  }
}

__global__ void offsets_kernel(const int* __restrict__ counts, int* __restrict__ off) {
  if (threadIdx.x == 0 && blockIdx.x == 0) {
    int o = 0; off[0] = 0;
    for (int e = 0; e < NEXP; ++e) { o += (counts[e] + ALGN - 1) & ~(ALGN - 1); off[e + 1] = o; }
  }
}

__global__ void scatter_kernel(const int* __restrict__ tki, const float* __restrict__ tkg,
                               const int* __restrict__ off, int* __restrict__ fill,
                               int* __restrict__ ptok, float* __restrict__ pgate,
                               int* __restrict__ inv) {
  const int t = blockIdx.x * 256 + threadIdx.x;
  if (t >= NUM_T) return;
#pragma unroll
  for (int k = 0; k < 2; ++k) {
    const int e = tki[t * 2 + k];
    const int pos = off[e] + atomicAdd(&fill[e], 1);
    ptok[pos] = t;
    pgate[pos] = tkg[t * 2 + k];
    inv[t * 2 + k] = pos;
  }
}

// =====================================================================
// fc GEMM: act = gelu(X[perm] @ Wfc[e]^T)
// m97-regime: 128x128 tile, 4 waves (2x2 of 64x64), BK=64, SINGLE-buffer
// 32 KB LDS, 2 barriers/K-step, plain C++ LDS reads (compiler waits),
// global_load_lds w16, XOR chunk swizzle, XCD chunk swizzle.
// launch_bounds(256,3): 3 waves/SIMD -> 3 blocks/CU; cross-block TLP
// hides the per-step barrier drain (m114/m97 mechanism).
// =====================================================================
__launch_bounds__(256, 3)
__global__ void fc_gemm(const unsigned short* __restrict__ xb,
                        const unsigned short* __restrict__ wfcb,
                        const int* __restrict__ ptok,
                        const int* __restrict__ off,
                        unsigned short* __restrict__ act) {
  const int nwg = (IDIM / 128) * RB;
  const int wgid = xcd_swz(blockIdx.x, nwg);
  const int row0 = (wgid / (IDIM / 128)) * 128;
  const int icol0 = (wgid % (IDIM / 128)) * 128;
  if (row0 >= off[8]) return;
  int e = 0;
  while (row0 >= off[e + 1]) ++e;

  __shared__ __align__(16) unsigned short Al[128 * 64];
  __shared__ __align__(16) unsigned short Bl[128 * 64];
  __shared__ int s_tok[128];

  const int tid = threadIdx.x;
  if (tid < 128) s_tok[tid] = ptok[row0 + tid];
  __syncthreads();

  // 4 A-loads + 4 B-loads per thread per K-step (16B each).
  // load id = p*256+tid: tile row r = id>>3, src chunk cs = (id&7)^(r&7)
  const unsigned short* gA[4];
  const unsigned short* gB[4];
#pragma unroll
  for (int p = 0; p < 4; ++p) {
    const int id = p * 256 + tid;
    const int r = id >> 3;
    const int cs = (id & 7) ^ (r & 7);
    gA[p] = xb + (size_t)s_tok[r] * HDIM + cs * 8;
    gB[p] = wfcb + ((size_t)e * IDIM + icol0 + r) * HDIM + cs * 8;
  }

  const int lane = tid & 63;
  const int wid = tid >> 6;
  const int wr = wid >> 1;
  const int wc = wid & 1;

  int aaddr[4], baddr[4];  // byte offsets (kk=0); kk=1 is ^64
#pragma unroll
  for (int m = 0; m < 4; ++m) {
    const int row = wr * 64 + m * 16 + (lane & 15);
    aaddr[m] = row * 128 + (((lane >> 4) ^ (row & 7)) * 16);
  }
#pragma unroll
  for (int n = 0; n < 4; ++n) {
    const int row = wc * 64 + n * 16 + (lane & 15);
    baddr[n] = row * 128 + (((lane >> 4) ^ (row & 7)) * 16);
  }

  f32x4 acc[4][4];
#pragma unroll
  for (int m = 0; m < 4; ++m)
#pragma unroll
    for (int n = 0; n < 4; ++n) acc[m][n] = (f32x4){0.f, 0.f, 0.f, 0.f};

  const int NS = HDIM / 64;
  for (int s = 0; s < NS; ++s) {
    const int k0 = s * 64;
    __syncthreads();               // prev step's reads done
#pragma unroll
    for (int p = 0; p < 4; ++p) {
      __builtin_amdgcn_global_load_lds(
          (const __attribute__((address_space(1))) void*)(gA[p] + k0),
          (__attribute__((address_space(3))) void*)((char*)Al + (p * 256 + tid) * 16), 16, 0, 0);
      __builtin_amdgcn_global_load_lds(
          (const __attribute__((address_space(1))) void*)(gB[p] + k0),
          (__attribute__((address_space(3))) void*)((char*)Bl + (p * 256 + tid) * 16), 16, 0, 0);
    }
    __syncthreads();               // stage landed (compiler drains vmcnt)
#pragma unroll
    for (int kk = 0; kk < 2; ++kk) {
      short8 a[4], b[4];
#pragma unroll
      for (int m = 0; m < 4; ++m) a[m] = *(const short8*)((const char*)Al + (aaddr[m] ^ (kk * 64)));
#pragma unroll
      for (int n = 0; n < 4; ++n) b[n] = *(const short8*)((const char*)Bl + (baddr[n] ^ (kk * 64)));
#pragma unroll
      for (int m = 0; m < 4; ++m)
#pragma unroll
        for (int n = 0; n < 4; ++n)
          acc[m][n] = __builtin_amdgcn_mfma_f32_16x16x32_bf16(a[m], b[n], acc[m][n], 0, 0, 0);
    }
  }

  // epilogue: exact gelu, bf16 store.  D: row=(lane>>4)*4+r, col=lane&15
#pragma unroll
  for (int m = 0; m < 4; ++m) {
    const int prow = row0 + wr * 64 + m * 16 + (lane >> 4) * 4;
#pragma unroll
    for (int n = 0; n < 4; ++n) {
      const int col = icol0 + wc * 64 + n * 16 + (lane & 15);
#pragma unroll
      for (int r = 0; r < 4; ++r) {
        const float v = acc[m][n][r];
        const float g = 0.5f * v * (1.0f + erff(v * 0.70710678118654752f));
        act[(size_t)(prow + r) * IDIM + col] = f32_to_bf16(g);
      }
    }
  }
}

// =====================================================================
// proj GEMM: pair[row] = gate * (act[row] @ Wproj[e]^T)
// Same m97-regime 128x128 structure; bf16 pair stores (no atomics).
// XCD swizzle keeps a row-panel's 8 col-blocks on one XCD -> L2 reuse.
// =====================================================================
__launch_bounds__(256, 3)
__global__ void proj_gemm(const unsigned short* __restrict__ actb,
                          const unsigned short* __restrict__ wpb,
                          const float* __restrict__ pgate,
                          const int* __restrict__ off,
                          unsigned short* __restrict__ pair) {
  const int nwg = (HDIM / 128) * RB;
  const int wgid = xcd_swz(blockIdx.x, nwg);
  const int row0 = (wgid / (HDIM / 128)) * 128;
  const int hcol0 = (wgid % (HDIM / 128)) * 128;
  if (row0 >= off[8]) return;
  int e = 0;
  while (row0 >= off[e + 1]) ++e;

  __shared__ __align__(16) unsigned short Al[128 * 64];
  __shared__ __align__(16) unsigned short Bl[128 * 64];
  __shared__ float s_g[128];

  const int tid = threadIdx.x;
  if (tid < 128) s_g[tid] = pgate[row0 + tid];
  __syncthreads();

  const unsigned short* gA[4];
  const unsigned short* gB[4];
#pragma unroll
  for (int p = 0; p < 4; ++p) {
    const int id = p * 256 + tid;
    const int r = id >> 3;
    const int cs = (id & 7) ^ (r & 7);
    gA[p] = actb + (size_t)(row0 + r) * IDIM + cs * 8;
    gB[p] = wpb + ((size_t)e * HDIM + hcol0 + r) * IDIM + cs * 8;
  }

  const int lane = tid & 63;
  const int wid = tid >> 6;
  const int wr = wid >> 1;
  const int wc = wid & 1;

  int aaddr[4], baddr[4];
#pragma unroll
  for (int m = 0; m < 4; ++m) {
    const int row = wr * 64 + m * 16 + (lane & 15);
    aaddr[m] = row * 128 + (((lane >> 4) ^ (row & 7)) * 16);
  }
#pragma unroll
  for (int n = 0; n < 4; ++n) {
    const int row = wc * 64 + n * 16 + (lane & 15);
    baddr[n] = row * 128 + (((lane >> 4) ^ (row & 7)) * 16);
  }

  f32x4 acc[4][4];
#pragma unroll
  for (int m = 0; m < 4; ++m)
#pragma unroll
    for (int n = 0; n < 4; ++n) acc[m][n] = (f32x4){0.f, 0.f, 0.f, 0.f};

  const int NS = IDIM / 64;
  for (int s = 0; s < NS; ++s) {
    const int k0 = s * 64;
    __syncthreads();
#pragma unroll
    for (int p = 0; p < 4; ++p) {
      __builtin_amdgcn_global_load_lds(
          (const __attribute__((address_space(1))) void*)(gA[p] + k0),
          (__attribute__((address_space(3))) void*)((char*)Al + (p * 256 + tid) * 16), 16, 0, 0);
      __builtin_amdgcn_global_load_lds(
          (const __attribute__((address_space(1))) void*)(gB[p] + k0),
          (__attribute__((address_space(3))) void*)((char*)Bl + (p * 256 + tid) * 16), 16, 0, 0);
    }
    __syncthreads();
#pragma unroll
    for (int kk = 0; kk < 2; ++kk) {
      short8 a[4], b[4];
#pragma unroll
      for (int m = 0; m < 4; ++m) a[m] = *(const short8*)((const char*)Al + (aaddr[m] ^ (kk * 64)));
#pragma unroll
      for (int n = 0; n < 4; ++n) b[n] = *(const short8*)((const char*)Bl + (baddr[n] ^ (kk * 64)));
#pragma unroll
      for (int m = 0; m < 4; ++m)
#pragma unroll
        for (int n = 0; n < 4; ++n)
          acc[m][n] = __builtin_amdgcn_mfma_f32_16x16x32_bf16(a[m], b[n], acc[m][n], 0, 0, 0);
    }
  }

  // epilogue: scale by gate, bf16 store into pair rows (pads have gate 0)
#pragma unroll
  for (int m = 0; m < 4; ++m) {
    const int lr = wr * 64 + m * 16 + (lane >> 4) * 4;
#pragma unroll
    for (int n = 0; n < 4; ++n) {
      const int col = hcol0 + wc * 64 + n * 16 + (lane & 15);
#pragma unroll
      for (int r = 0; r < 4; ++r) {
        const float g = s_g[lr + r];
        pair[(size_t)(row0 + lr + r) * HDIM + col] = f32_to_bf16(g * acc[m][n][r]);
      }
    }
  }
}

// ---------------- combine: out[t] = pair[inv[t,0]] + pair[inv[t,1]] ----------------
__global__ void combine_kernel(const unsigned short* __restrict__ pair,
                               const int* __restrict__ inv, float* __restrict__ out) {
  const int gid = blockIdx.x * 256 + threadIdx.x;     // NUM_T*HDIM/8 threads
  const int t = gid >> 7;
  const int c8 = (gid & 127) << 3;
  const short8 v0 = *(const short8*)(pair + (size_t)inv[t * 2] * HDIM + c8);
  const short8 v1 = *(const short8*)(pair + (size_t)inv[t * 2 + 1] * HDIM + c8);
  float o[8];
#pragma unroll
  for (int j = 0; j < 8; ++j)
    o[j] = bf16_to_f32((unsigned short)v0[j]) + bf16_to_f32((unsigned short)v1[j]);
  float* dst = out + (size_t)t * HDIM + c8;
  ((float4*)dst)[0] = (float4){o[0], o[1], o[2], o[3]};
  ((float4*)dst)[1] = (float4){o[4], o[5], o[6], o[7]};
}

extern "C" void kernel_launch(void* const* d_in, const int* in_sizes, int n_in,
                              void* d_out, int out_size, void* d_ws, size_t ws_size,
                              hipStream_t stream) {
  const float* x   = (const float*)d_in[0];
  const float* wg  = (const float*)d_in[1];
  const float* wfc = (const float*)d_in[2];
  const float* wpj = (const float*)d_in[3];
  float* out    = (float*)d_out;
  float* logits = out + (size_t)NUM_T * HDIM;

  char* p = (char*)d_ws;
  auto alloc = [&](size_t bytes) { char* q = p; p += (bytes + 255) & ~size_t(255); return q; };
  unsigned short* xb    = (unsigned short*)alloc((size_t)NUM_T * HDIM * 2);
  unsigned short* wfcb  = (unsigned short*)alloc((size_t)NEXP * IDIM * HDIM * 2);
  unsigned short* wpb   = (unsigned short*)alloc((size_t)NEXP * HDIM * IDIM * 2);
  unsigned short* act   = (unsigned short*)alloc((size_t)MAXROWS * IDIM * 2);
  unsigned short* pair  = (unsigned short*)alloc((size_t)MAXROWS * HDIM * 2);
  int*            ptok  = (int*)alloc((size_t)MAXROWS * 4);
  float*          pgate = (float*)alloc((size_t)MAXROWS * 4);
  int*            tki   = (int*)alloc((size_t)NUM_T * 2 * 4);
  float*          tkg   = (float*)alloc((size_t)NUM_T * 2 * 4);
  int*            inv   = (int*)alloc((size_t)NUM_T * 2 * 4);
  int*            counts= (int*)alloc(64);
  int*            fill  = (int*)alloc(64);
  int*            off   = (int*)alloc(64);
  const size_t need = (size_t)(p - (char*)d_ws);
  if (need > ws_size) {
    fprintf(stderr, "kernel_launch: ws too small: need %zu have %zu\n", need, ws_size);
    hipMemsetAsync(d_out, 0, (size_t)out_size * 4, stream);
    return;
  }

  // zero aux region (pads -> token 0 / gate 0; counts/fill for atomics)
  hipMemsetAsync(ptok, 0, (size_t)(p - (char*)ptok), stream);

  cvt_kernel<<<2048, 256, 0, stream>>>(wfc, wfcb, NEXP * IDIM * HDIM / 4);
  cvt_kernel<<<2048, 256, 0, stream>>>(wpj, wpb,  NEXP * HDIM * IDIM / 4);

  router_kernel<<<NUM_T / 4, 256, 0, stream>>>(x, wg, logits, tki, tkg, counts, xb);
  offsets_kernel<<<1, 64, 0, stream>>>(counts, off);
  scatter_kernel<<<NUM_T / 256, 256, 0, stream>>>(tki, tkg, off, fill, ptok, pgate, inv);

  fc_gemm<<<(IDIM / 128) * RB, 256, 0, stream>>>(xb, wfcb, ptok, off, act);
  proj_gemm<<<(HDIM / 128) * RB, 256, 0, stream>>>(act, wpb, pgate, off, pair);
  combine_kernel<<<NUM_T * HDIM / 8 / 256, 256, 0, stream>>>(pair, inv, out);
}

// Round 9
// 713.707 us; speedup vs baseline: 1.3160x; 1.0045x over previous
//
#include <hip/hip_runtime.h>
#include <hip/hip_bf16.h>
#include <cstdint>
#include <cstdio>

#define NUM_T   8192
#define HDIM    1024
#define IDIM    4096
#define NEXP    8

#define ALGN    128                 // expert group alignment (= tile M)
#define RB      136                 // ceil((16384 + 8*127)/128)
#define MAXROWS (RB * 128)          // 17408 padded pair-rows

typedef __attribute__((ext_vector_type(8))) short short8;
typedef __attribute__((ext_vector_type(4))) float f32x4;

__device__ __forceinline__ unsigned short f32_to_bf16(float f) {
  uint32_t u = __float_as_uint(f);
  u += 0x7fffu + ((u >> 16) & 1u);   // RNE; inputs are finite
  return (unsigned short)(u >> 16);
}
__device__ __forceinline__ float bf16_to_f32(unsigned short u) {
  return __uint_as_float(((uint32_t)u) << 16);
}
// bijective XCD swizzle: launch-order bid -> logical wgid, 8 contiguous chunks
__device__ __forceinline__ int xcd_swz(int bid, int nwg) {
  const int q = nwg >> 3, r = nwg & 7;
  const int x = bid & 7, i = bid >> 3;
  return (x < r ? x * (q + 1) : r * (q + 1) + (x - r) * q) + i;
}

// ---------------- fp32 -> bf16 convert, both weight tensors in one launch ----------------
__global__ void cvt2_kernel(const float* __restrict__ in0, unsigned short* __restrict__ out0,
                            int n4_0,
                            const float* __restrict__ in1, unsigned short* __restrict__ out1,
                            int n4_total) {
  int i = blockIdx.x * blockDim.x + threadIdx.x;
  const int stride = gridDim.x * blockDim.x;
  for (; i < n4_total; i += stride) {
    const float* in  = (i < n4_0) ? in0  : in1;
    unsigned short* out = (i < n4_0) ? out0 : out1;
    const int j = (i < n4_0) ? i : i - n4_0;
    const float4 v = ((const float4*)in)[j];
    ushort4 o;
    o.x = f32_to_bf16(v.x); o.y = f32_to_bf16(v.y);
    o.z = f32_to_bf16(v.z); o.w = f32_to_bf16(v.w);
    ((ushort4*)out)[j] = o;
  }
}

// ---------------- router: logits fp32, top-2 softmax, counts; emits xb ----------------
__global__ void router_kernel(const float* __restrict__ x, const float* __restrict__ wg,
                              float* __restrict__ logits, int* __restrict__ tki,
                              float* __restrict__ tkg, int* __restrict__ counts,
                              unsigned short* __restrict__ xb) {
  const int t = blockIdx.x * 4 + (threadIdx.x >> 6);   // one wave per token
  const int lane = threadIdx.x & 63;
  const float* xr = x + (size_t)t * HDIM;
  unsigned short* xbr = xb + (size_t)t * HDIM;
  float acc[NEXP];
#pragma unroll
  for (int e = 0; e < NEXP; ++e) acc[e] = 0.f;
  for (int h = lane; h < HDIM; h += 64) {
    const float xv = xr[h];
    xbr[h] = f32_to_bf16(xv);          // fused x -> bf16
#pragma unroll
    for (int e = 0; e < NEXP; ++e) acc[e] += xv * wg[e * HDIM + h];
  }
#pragma unroll
  for (int e = 0; e < NEXP; ++e) {
#pragma unroll
    for (int s = 32; s > 0; s >>= 1) acc[e] += __shfl_xor(acc[e], s, 64);
  }
  if (lane == 0) {
    float v0 = -1e30f, v1 = -1e30f; int i0 = 0, i1 = 0;
#pragma unroll
    for (int e = 0; e < NEXP; ++e) {
      const float v = acc[e];
      logits[(size_t)t * NEXP + e] = v;
      if (v > v0)      { v1 = v0; i1 = i0; v0 = v; i0 = e; }
      else if (v > v1) { v1 = v; i1 = e; }
    }
    const float g0 = 1.f / (1.f + expf(v1 - v0));  // softmax over top-2
    tki[t * 2] = i0; tki[t * 2 + 1] = i1;
    tkg[t * 2] = g0; tkg[t * 2 + 1] = 1.f - g0;
    atomicAdd(&counts[i0], 1);
    atomicAdd(&counts[i1], 1);
  }
}

__global__ void offsets_kernel(const int* __restrict__ counts, int* __restrict__ off) {
  if (threadIdx.x == 0 && blockIdx.x == 0) {
    int o = 0; off[0] = 0;
    for (int e = 0; e < NEXP; ++e) { o += (counts[e] + ALGN - 1) & ~(ALGN - 1); off[e + 1] = o; }
  }
}

__global__ void scatter_kernel(const int* __restrict__ tki, const float* __restrict__ tkg,
                               const int* __restrict__ off, int* __restrict__ fill,
                               int* __restrict__ ptok, float* __restrict__ pgate,
                               int* __restrict__ inv) {
  const int t = blockIdx.x * 256 + threadIdx.x;
  if (t >= NUM_T) return;
#pragma unroll
  for (int k = 0; k < 2; ++k) {
    const int e = tki[t * 2 + k];
    const int pos = off[e] + atomicAdd(&fill[e], 1);
    ptok[pos] = t;
    pgate[pos] = tkg[t * 2 + k];
    inv[t * 2 + k] = pos;
  }
}

// =====================================================================
// fc GEMM: act = gelu(X[perm] @ Wfc[e]^T)
// m97-regime: 128x128 tile, 4 waves, BK=64, single-buffer 32 KB LDS,
// 2 barriers/K-step, plain C++ LDS reads, global_load_lds w16,
// XOR chunk swizzle, XCD chunk swizzle.
// launch_bounds(256,4): cap VGPR<=64 (now 60) -> 4 blocks/CU
// (LDS 4x33KB=133<=160, regs 64+64acc=128<=512/4). Max cross-block TLP.
// =====================================================================
__launch_bounds__(256, 4)
__global__ void fc_gemm(const unsigned short* __restrict__ xb,
                        const unsigned short* __restrict__ wfcb,
                        const int* __restrict__ ptok,
                        const int* __restrict__ off,
                        unsigned short* __restrict__ act) {
  const int nwg = (IDIM / 128) * RB;
  const int wgid = xcd_swz(blockIdx.x, nwg);
  const int row0 = (wgid / (IDIM / 128)) * 128;
  const int icol0 = (wgid % (IDIM / 128)) * 128;
  if (row0 >= off[8]) return;
  int e = 0;
  while (row0 >= off[e + 1]) ++e;

  __shared__ __align__(16) unsigned short Al[128 * 64];
  __shared__ __align__(16) unsigned short Bl[128 * 64];
  __shared__ int s_tok[128];

  const int tid = threadIdx.x;
  if (tid < 128) s_tok[tid] = ptok[row0 + tid];
  __syncthreads();

  // 4 A-loads + 4 B-loads per thread per K-step (16B each).
  // load id = p*256+tid: tile row r = id>>3, src chunk cs = (id&7)^(r&7)
  const unsigned short* gA[4];
  const unsigned short* gB[4];
#pragma unroll
  for (int p = 0; p < 4; ++p) {
    const int id = p * 256 + tid;
    const int r = id >> 3;
    const int cs = (id & 7) ^ (r & 7);
    gA[p] = xb + (size_t)s_tok[r] * HDIM + cs * 8;
    gB[p] = wfcb + ((size_t)e * IDIM + icol0 + r) * HDIM + cs * 8;
  }

  const int lane = tid & 63;
  const int wid = tid >> 6;
  const int wr = wid >> 1;
  const int wc = wid & 1;

  int aaddr[4], baddr[4];  // byte offsets (kk=0); kk=1 is ^64
#pragma unroll
  for (int m = 0; m < 4; ++m) {
    const int row = wr * 64 + m * 16 + (lane & 15);
    aaddr[m] = row * 128 + (((lane >> 4) ^ (row & 7)) * 16);
  }
#pragma unroll
  for (int n = 0; n < 4; ++n) {
    const int row = wc * 64 + n * 16 + (lane & 15);
    baddr[n] = row * 128 + (((lane >> 4) ^ (row & 7)) * 16);
  }

  f32x4 acc[4][4];
#pragma unroll
  for (int m = 0; m < 4; ++m)
#pragma unroll
    for (int n = 0; n < 4; ++n) acc[m][n] = (f32x4){0.f, 0.f, 0.f, 0.f};

  const int NS = HDIM / 64;
  for (int s = 0; s < NS; ++s) {
    const int k0 = s * 64;
    __syncthreads();               // prev step's reads done
#pragma unroll
    for (int p = 0; p < 4; ++p) {
      __builtin_amdgcn_global_load_lds(
          (const __attribute__((address_space(1))) void*)(gA[p] + k0),
          (__attribute__((address_space(3))) void*)((char*)Al + (p * 256 + tid) * 16), 16, 0, 0);
      __builtin_amdgcn_global_load_lds(
          (const __attribute__((address_space(1))) void*)(gB[p] + k0),
          (__attribute__((address_space(3))) void*)((char*)Bl + (p * 256 + tid) * 16), 16, 0, 0);
    }
    __syncthreads();               // stage landed (compiler drains vmcnt)
#pragma unroll
    for (int kk = 0; kk < 2; ++kk) {
      short8 a[4], b[4];
#pragma unroll
      for (int m = 0; m < 4; ++m) a[m] = *(const short8*)((const char*)Al + (aaddr[m] ^ (kk * 64)));
#pragma unroll
      for (int n = 0; n < 4; ++n) b[n] = *(const short8*)((const char*)Bl + (baddr[n] ^ (kk * 64)));
#pragma unroll
      for (int m = 0; m < 4; ++m)
#pragma unroll
        for (int n = 0; n < 4; ++n)
          acc[m][n] = __builtin_amdgcn_mfma_f32_16x16x32_bf16(a[m], b[n], acc[m][n], 0, 0, 0);
    }
  }

  // epilogue: exact gelu, bf16 store.  D: row=(lane>>4)*4+r, col=lane&15
#pragma unroll
  for (int m = 0; m < 4; ++m) {
    const int prow = row0 + wr * 64 + m * 16 + (lane >> 4) * 4;
#pragma unroll
    for (int n = 0; n < 4; ++n) {
      const int col = icol0 + wc * 64 + n * 16 + (lane & 15);
#pragma unroll
      for (int r = 0; r < 4; ++r) {
        const float v = acc[m][n][r];
        const float g = 0.5f * v * (1.0f + erff(v * 0.70710678118654752f));
        act[(size_t)(prow + r) * IDIM + col] = f32_to_bf16(g);
      }
    }
  }
}

// =====================================================================
// proj GEMM: pair[row] = gate * (act[row] @ Wproj[e]^T)
// Same m97-regime 128x128 structure; bf16 pair stores (no atomics).
// =====================================================================
__launch_bounds__(256, 4)
__global__ void proj_gemm(const unsigned short* __restrict__ actb,
                          const unsigned short* __restrict__ wpb,
                          const float* __restrict__ pgate,
                          const int* __restrict__ off,
                          unsigned short* __restrict__ pair) {
  const int nwg = (HDIM / 128) * RB;
  const int wgid = xcd_swz(blockIdx.x, nwg);
  const int row0 = (wgid / (HDIM / 128)) * 128;
  const int hcol0 = (wgid % (HDIM / 128)) * 128;
  if (row0 >= off[8]) return;
  int e = 0;
  while (row0 >= off[e + 1]) ++e;

  __shared__ __align__(16) unsigned short Al[128 * 64];
  __shared__ __align__(16) unsigned short Bl[128 * 64];
  __shared__ float s_g[128];

  const int tid = threadIdx.x;
  if (tid < 128) s_g[tid] = pgate[row0 + tid];
  __syncthreads();

  const unsigned short* gA[4];
  const unsigned short* gB[4];
#pragma unroll
  for (int p = 0; p < 4; ++p) {
    const int id = p * 256 + tid;
    const int r = id >> 3;
    const int cs = (id & 7) ^ (r & 7);
    gA[p] = actb + (size_t)(row0 + r) * IDIM + cs * 8;
    gB[p] = wpb + ((size_t)e * HDIM + hcol0 + r) * IDIM + cs * 8;
  }

  const int lane = tid & 63;
  const int wid = tid >> 6;
  const int wr = wid >> 1;
  const int wc = wid & 1;

  int aaddr[4], baddr[4];
#pragma unroll
  for (int m = 0; m < 4; ++m) {
    const int row = wr * 64 + m * 16 + (lane & 15);
    aaddr[m] = row * 128 + (((lane >> 4) ^ (row & 7)) * 16);
  }
#pragma unroll
  for (int n = 0; n < 4; ++n) {
    const int row = wc * 64 + n * 16 + (lane & 15);
    baddr[n] = row * 128 + (((lane >> 4) ^ (row & 7)) * 16);
  }

  f32x4 acc[4][4];
#pragma unroll
  for (int m = 0; m < 4; ++m)
#pragma unroll
    for (int n = 0; n < 4; ++n) acc[m][n] = (f32x4){0.f, 0.f, 0.f, 0.f};

  const int NS = IDIM / 64;
  for (int s = 0; s < NS; ++s) {
    const int k0 = s * 64;
    __syncthreads();
#pragma unroll
    for (int p = 0; p < 4; ++p) {
      __builtin_amdgcn_global_load_lds(
          (const __attribute__((address_space(1))) void*)(gA[p] + k0),
          (__attribute__((address_space(3))) void*)((char*)Al + (p * 256 + tid) * 16), 16, 0, 0);
      __builtin_amdgcn_global_load_lds(
          (const __attribute__((address_space(1))) void*)(gB[p] + k0),
          (__attribute__((address_space(3))) void*)((char*)Bl + (p * 256 + tid) * 16), 16, 0, 0);
    }
    __syncthreads();
#pragma unroll
    for (int kk = 0; kk < 2; ++kk) {
      short8 a[4], b[4];
#pragma unroll
      for (int m = 0; m < 4; ++m) a[m] = *(const short8*)((const char*)Al + (aaddr[m] ^ (kk * 64)));
#pragma unroll
      for (int n = 0; n < 4; ++n) b[n] = *(const short8*)((const char*)Bl + (baddr[n] ^ (kk * 64)));
#pragma unroll
      for (int m = 0; m < 4; ++m)
#pragma unroll
        for (int n = 0; n < 4; ++n)
          acc[m][n] = __builtin_amdgcn_mfma_f32_16x16x32_bf16(a[m], b[n], acc[m][n], 0, 0, 0);
    }
  }

  // epilogue: scale by gate, bf16 store into pair rows (pads have gate 0)
#pragma unroll
  for (int m = 0; m < 4; ++m) {
    const int lr = wr * 64 + m * 16 + (lane >> 4) * 4;
#pragma unroll
    for (int n = 0; n < 4; ++n) {
      const int col = hcol0 + wc * 64 + n * 16 + (lane & 15);
#pragma unroll
      for (int r = 0; r < 4; ++r) {
        const float g = s_g[lr + r];
        pair[(size_t)(row0 + lr + r) * HDIM + col] = f32_to_bf16(g * acc[m][n][r]);
      }
    }
  }
}

// ---------------- combine: out[t] = pair[inv[t,0]] + pair[inv[t,1]] ----------------
__global__ void combine_kernel(const unsigned short* __restrict__ pair,
                               const int* __restrict__ inv, float* __restrict__ out) {
  const int gid = blockIdx.x * 256 + threadIdx.x;     // NUM_T*HDIM/8 threads
  const int t = gid >> 7;
  const int c8 = (gid & 127) << 3;
  const short8 v0 = *(const short8*)(pair + (size_t)inv[t * 2] * HDIM + c8);
  const short8 v1 = *(const short8*)(pair + (size_t)inv[t * 2 + 1] * HDIM + c8);
  float o[8];
#pragma unroll
  for (int j = 0; j < 8; ++j)
    o[j] = bf16_to_f32((unsigned short)v0[j]) + bf16_to_f32((unsigned short)v1[j]);
  float* dst = out + (size_t)t * HDIM + c8;
  ((float4*)dst)[0] = (float4){o[0], o[1], o[2], o[3]};
  ((float4*)dst)[1] = (float4){o[4], o[5], o[6], o[7]};
}

extern "C" void kernel_launch(void* const* d_in, const int* in_sizes, int n_in,
                              void* d_out, int out_size, void* d_ws, size_t ws_size,
                              hipStream_t stream) {
  const float* x   = (const float*)d_in[0];
  const float* wg  = (const float*)d_in[1];
  const float* wfc = (const float*)d_in[2];
  const float* wpj = (const float*)d_in[3];
  float* out    = (float*)d_out;
  float* logits = out + (size_t)NUM_T * HDIM;

  char* p = (char*)d_ws;
  auto alloc = [&](size_t bytes) { char* q = p; p += (bytes + 255) & ~size_t(255); return q; };
  unsigned short* xb    = (unsigned short*)alloc((size_t)NUM_T * HDIM * 2);
  unsigned short* wfcb  = (unsigned short*)alloc((size_t)NEXP * IDIM * HDIM * 2);
  unsigned short* wpb   = (unsigned short*)alloc((size_t)NEXP * HDIM * IDIM * 2);
  unsigned short* act   = (unsigned short*)alloc((size_t)MAXROWS * IDIM * 2);
  unsigned short* pair  = (unsigned short*)alloc((size_t)MAXROWS * HDIM * 2);
  int*            ptok  = (int*)alloc((size_t)MAXROWS * 4);
  float*          pgate = (float*)alloc((size_t)MAXROWS * 4);
  int*            tki   = (int*)alloc((size_t)NUM_T * 2 * 4);
  float*          tkg   = (float*)alloc((size_t)NUM_T * 2 * 4);
  int*            inv   = (int*)alloc((size_t)NUM_T * 2 * 4);
  int*            counts= (int*)alloc(64);
  int*            fill  = (int*)alloc(64);
  int*            off   = (int*)alloc(64);
  const size_t need = (size_t)(p - (char*)d_ws);
  if (need > ws_size) {
    fprintf(stderr, "kernel_launch: ws too small: need %zu have %zu\n", need, ws_size);
    hipMemsetAsync(d_out, 0, (size_t)out_size * 4, stream);
    return;
  }

  // zero aux region (pads -> token 0 / gate 0; counts/fill for atomics)
  hipMemsetAsync(ptok, 0, (size_t)(p - (char*)ptok), stream);

  const int n4w = NEXP * IDIM * HDIM / 4;
  cvt2_kernel<<<4096, 256, 0, stream>>>(wfc, wfcb, n4w, wpj, wpb, 2 * n4w);

  router_kernel<<<NUM_T / 4, 256, 0, stream>>>(x, wg, logits, tki, tkg, counts, xb);
  offsets_kernel<<<1, 64, 0, stream>>>(counts, off);
  scatter_kernel<<<NUM_T / 256, 256, 0, stream>>>(tki, tkg, off, fill, ptok, pgate, inv);

  fc_gemm<<<(IDIM / 128) * RB, 256, 0, stream>>>(xb, wfcb, ptok, off, act);
  proj_gemm<<<(HDIM / 128) * RB, 256, 0, stream>>>(act, wpb, pgate, off, pair);
  combine_kernel<<<NUM_T * HDIM / 8 / 256, 256, 0, stream>>>(pair, inv, out);
}

// Round 10
// 553.636 us; speedup vs baseline: 1.6965x; 1.2891x over previous
//
#include <hip/hip_runtime.h>
#include <hip/hip_bf16.h>
#include <cstdint>
#include <cstdio>

#define NUM_T   8192
#define HDIM    1024
#define IDIM    4096
#define NEXP    8

#define ALGN    128                 // expert group alignment (= tile M)
#define RB      136                 // ceil((16384 + 8*127)/128)
#define MAXROWS (RB * 128)          // 17408 padded pair-rows
#define TPB     16                  // router tokens per block

typedef __attribute__((ext_vector_type(8))) short short8;
typedef __attribute__((ext_vector_type(4))) float f32x4;

__device__ __forceinline__ unsigned short f32_to_bf16(float f) {
  uint32_t u = __float_as_uint(f);
  u += 0x7fffu + ((u >> 16) & 1u);   // RNE; inputs are finite
  return (unsigned short)(u >> 16);
}
__device__ __forceinline__ float bf16_to_f32(unsigned short u) {
  return __uint_as_float(((uint32_t)u) << 16);
}
// bijective XCD swizzle: launch-order bid -> logical wgid, 8 contiguous chunks
__device__ __forceinline__ int xcd_swz(int bid, int nwg) {
  const int q = nwg >> 3, r = nwg & 7;
  const int x = bid & 7, i = bid >> 3;
  return (x < r ? x * (q + 1) : r * (q + 1) + (x - r) * q) + i;
}

// ---------------- fp32 -> bf16 convert, both weight tensors in one launch ----------------
__global__ void cvt2_kernel(const float* __restrict__ in0, unsigned short* __restrict__ out0,
                            int n4_0,
                            const float* __restrict__ in1, unsigned short* __restrict__ out1,
                            int n4_total) {
  int i = blockIdx.x * blockDim.x + threadIdx.x;
  const int stride = gridDim.x * blockDim.x;
  for (; i < n4_total; i += stride) {
    const float* in  = (i < n4_0) ? in0  : in1;
    unsigned short* out = (i < n4_0) ? out0 : out1;
    const int j = (i < n4_0) ? i : i - n4_0;
    const float4 v = ((const float4*)in)[j];
    ushort4 o;
    o.x = f32_to_bf16(v.x); o.y = f32_to_bf16(v.y);
    o.z = f32_to_bf16(v.z); o.w = f32_to_bf16(v.w);
    ((ushort4*)out)[j] = o;
  }
}

// ---------------- router (rewritten): float4 loads, 4 tokens/wave,
// block-reduced expert counts; fused x->bf16 ----------------
__global__ void router_kernel(const float* __restrict__ x, const float* __restrict__ wg,
                              float* __restrict__ logits, int* __restrict__ tki,
                              float* __restrict__ tkg, int* __restrict__ counts,
                              unsigned short* __restrict__ xb) {
  __shared__ int s_cnt[NEXP];
  const int tid = threadIdx.x;
  if (tid < NEXP) s_cnt[tid] = 0;
  __syncthreads();

  const int wave = tid >> 6;
  const int lane = tid & 63;

#pragma unroll 1
  for (int k = 0; k < 4; ++k) {
    const int t = blockIdx.x * TPB + wave * 4 + k;
    const float* xr = x + (size_t)t * HDIM;
    unsigned short* xbr = xb + (size_t)t * HDIM;

    float acc[NEXP];
#pragma unroll
    for (int e = 0; e < NEXP; ++e) acc[e] = 0.f;

#pragma unroll
    for (int it = 0; it < 4; ++it) {
      const int off = it * 256 + lane * 4;
      const float4 xv = *(const float4*)(xr + off);
      ushort4 o;
      o.x = f32_to_bf16(xv.x); o.y = f32_to_bf16(xv.y);
      o.z = f32_to_bf16(xv.z); o.w = f32_to_bf16(xv.w);
      *(ushort4*)(xbr + off) = o;
#pragma unroll
      for (int e = 0; e < NEXP; ++e) {
        const float4 wv = *(const float4*)(wg + e * HDIM + off);
        acc[e] += xv.x * wv.x + xv.y * wv.y + xv.z * wv.z + xv.w * wv.w;
      }
    }
#pragma unroll
    for (int e = 0; e < NEXP; ++e) {
#pragma unroll
      for (int s = 32; s > 0; s >>= 1) acc[e] += __shfl_xor(acc[e], s, 64);
    }
    if (lane == 0) {
      float v0 = -1e30f, v1 = -1e30f; int i0 = 0, i1 = 0;
#pragma unroll
      for (int e = 0; e < NEXP; ++e) {
        const float v = acc[e];
        logits[(size_t)t * NEXP + e] = v;
        if (v > v0)      { v1 = v0; i1 = i0; v0 = v; i0 = e; }
        else if (v > v1) { v1 = v; i1 = e; }
      }
      const float g0 = 1.f / (1.f + expf(v1 - v0));  // softmax over top-2
      tki[t * 2] = i0; tki[t * 2 + 1] = i1;
      tkg[t * 2] = g0; tkg[t * 2 + 1] = 1.f - g0;
      atomicAdd(&s_cnt[i0], 1);
      atomicAdd(&s_cnt[i1], 1);
    }
  }
  __syncthreads();
  if (tid < NEXP) atomicAdd(&counts[tid], s_cnt[tid]);
}

__global__ void offsets_kernel(const int* __restrict__ counts, int* __restrict__ off) {
  if (threadIdx.x == 0 && blockIdx.x == 0) {
    int o = 0; off[0] = 0;
    for (int e = 0; e < NEXP; ++e) { o += (counts[e] + ALGN - 1) & ~(ALGN - 1); off[e + 1] = o; }
  }
}

__global__ void scatter_kernel(const int* __restrict__ tki, const float* __restrict__ tkg,
                               const int* __restrict__ off, int* __restrict__ fill,
                               int* __restrict__ ptok, float* __restrict__ pgate,
                               int* __restrict__ inv) {
  const int t = blockIdx.x * 256 + threadIdx.x;
  if (t >= NUM_T) return;
#pragma unroll
  for (int k = 0; k < 2; ++k) {
    const int e = tki[t * 2 + k];
    const int pos = off[e] + atomicAdd(&fill[e], 1);
    ptok[pos] = t;
    pgate[pos] = tkg[t * 2 + k];
    inv[t * 2 + k] = pos;
  }
}

// =====================================================================
// fc GEMM: act = gelu(X[perm] @ Wfc[e]^T)
// m97-regime: 128x128 tile, 4 waves, BK=64, single-buffer 32 KB LDS,
// 2 barriers/K-step, plain C++ LDS reads, global_load_lds w16,
// XOR chunk swizzle, XCD chunk swizzle. (256,4): 4 blocks/CU.
// =====================================================================
__launch_bounds__(256, 4)
__global__ void fc_gemm(const unsigned short* __restrict__ xb,
                        const unsigned short* __restrict__ wfcb,
                        const int* __restrict__ ptok,
                        const int* __restrict__ off,
                        unsigned short* __restrict__ act) {
  const int nwg = (IDIM / 128) * RB;
  const int wgid = xcd_swz(blockIdx.x, nwg);
  const int row0 = (wgid / (IDIM / 128)) * 128;
  const int icol0 = (wgid % (IDIM / 128)) * 128;
  if (row0 >= off[8]) return;
  int e = 0;
  while (row0 >= off[e + 1]) ++e;

  __shared__ __align__(16) unsigned short Al[128 * 64];
  __shared__ __align__(16) unsigned short Bl[128 * 64];
  __shared__ int s_tok[128];

  const int tid = threadIdx.x;
  if (tid < 128) s_tok[tid] = ptok[row0 + tid];
  __syncthreads();

  const unsigned short* gA[4];
  const unsigned short* gB[4];
#pragma unroll
  for (int p = 0; p < 4; ++p) {
    const int id = p * 256 + tid;
    const int r = id >> 3;
    const int cs = (id & 7) ^ (r & 7);
    gA[p] = xb + (size_t)s_tok[r] * HDIM + cs * 8;
    gB[p] = wfcb + ((size_t)e * IDIM + icol0 + r) * HDIM + cs * 8;
  }

  const int lane = tid & 63;
  const int wid = tid >> 6;
  const int wr = wid >> 1;
  const int wc = wid & 1;

  int aaddr[4], baddr[4];  // byte offsets (kk=0); kk=1 is ^64
#pragma unroll
  for (int m = 0; m < 4; ++m) {
    const int row = wr * 64 + m * 16 + (lane & 15);
    aaddr[m] = row * 128 + (((lane >> 4) ^ (row & 7)) * 16);
  }
#pragma unroll
  for (int n = 0; n < 4; ++n) {
    const int row = wc * 64 + n * 16 + (lane & 15);
    baddr[n] = row * 128 + (((lane >> 4) ^ (row & 7)) * 16);
  }

  f32x4 acc[4][4];
#pragma unroll
  for (int m = 0; m < 4; ++m)
#pragma unroll
    for (int n = 0; n < 4; ++n) acc[m][n] = (f32x4){0.f, 0.f, 0.f, 0.f};

  const int NS = HDIM / 64;
  for (int s = 0; s < NS; ++s) {
    const int k0 = s * 64;
    __syncthreads();               // prev step's reads done
#pragma unroll
    for (int p = 0; p < 4; ++p) {
      __builtin_amdgcn_global_load_lds(
          (const __attribute__((address_space(1))) void*)(gA[p] + k0),
          (__attribute__((address_space(3))) void*)((char*)Al + (p * 256 + tid) * 16), 16, 0, 0);
      __builtin_amdgcn_global_load_lds(
          (const __attribute__((address_space(1))) void*)(gB[p] + k0),
          (__attribute__((address_space(3))) void*)((char*)Bl + (p * 256 + tid) * 16), 16, 0, 0);
    }
    __syncthreads();               // stage landed (compiler drains vmcnt)
#pragma unroll
    for (int kk = 0; kk < 2; ++kk) {
      short8 a[4], b[4];
#pragma unroll
      for (int m = 0; m < 4; ++m) a[m] = *(const short8*)((const char*)Al + (aaddr[m] ^ (kk * 64)));
#pragma unroll
      for (int n = 0; n < 4; ++n) b[n] = *(const short8*)((const char*)Bl + (baddr[n] ^ (kk * 64)));
#pragma unroll
      for (int m = 0; m < 4; ++m)
#pragma unroll
        for (int n = 0; n < 4; ++n)
          acc[m][n] = __builtin_amdgcn_mfma_f32_16x16x32_bf16(a[m], b[n], acc[m][n], 0, 0, 0);
    }
  }

  // epilogue: exact gelu, bf16 store.  D: row=(lane>>4)*4+r, col=lane&15
#pragma unroll
  for (int m = 0; m < 4; ++m) {
    const int prow = row0 + wr * 64 + m * 16 + (lane >> 4) * 4;
#pragma unroll
    for (int n = 0; n < 4; ++n) {
      const int col = icol0 + wc * 64 + n * 16 + (lane & 15);
#pragma unroll
      for (int r = 0; r < 4; ++r) {
        const float v = acc[m][n][r];
        const float g = 0.5f * v * (1.0f + erff(v * 0.70710678118654752f));
        act[(size_t)(prow + r) * IDIM + col] = f32_to_bf16(g);
      }
    }
  }
}

// =====================================================================
// proj GEMM: pair[row] = gate * (act[row] @ Wproj[e]^T)
// Same m97-regime 128x128 structure; bf16 pair stores (no atomics).
// =====================================================================
__launch_bounds__(256, 4)
__global__ void proj_gemm(const unsigned short* __restrict__ actb,
                          const unsigned short* __restrict__ wpb,
                          const float* __restrict__ pgate,
                          const int* __restrict__ off,
                          unsigned short* __restrict__ pair) {
  const int nwg = (HDIM / 128) * RB;
  const int wgid = xcd_swz(blockIdx.x, nwg);
  const int row0 = (wgid / (HDIM / 128)) * 128;
  const int hcol0 = (wgid % (HDIM / 128)) * 128;
  if (row0 >= off[8]) return;
  int e = 0;
  while (row0 >= off[e + 1]) ++e;

  __shared__ __align__(16) unsigned short Al[128 * 64];
  __shared__ __align__(16) unsigned short Bl[128 * 64];
  __shared__ float s_g[128];

  const int tid = threadIdx.x;
  if (tid < 128) s_g[tid] = pgate[row0 + tid];
  __syncthreads();

  const unsigned short* gA[4];
  const unsigned short* gB[4];
#pragma unroll
  for (int p = 0; p < 4; ++p) {
    const int id = p * 256 + tid;
    const int r = id >> 3;
    const int cs = (id & 7) ^ (r & 7);
    gA[p] = actb + (size_t)(row0 + r) * IDIM + cs * 8;
    gB[p] = wpb + ((size_t)e * HDIM + hcol0 + r) * IDIM + cs * 8;
  }

  const int lane = tid & 63;
  const int wid = tid >> 6;
  const int wr = wid >> 1;
  const int wc = wid & 1;

  int aaddr[4], baddr[4];
#pragma unroll
  for (int m = 0; m < 4; ++m) {
    const int row = wr * 64 + m * 16 + (lane & 15);
    aaddr[m] = row * 128 + (((lane >> 4) ^ (row & 7)) * 16);
  }
#pragma unroll
  for (int n = 0; n < 4; ++n) {
    const int row = wc * 64 + n * 16 + (lane & 15);
    baddr[n] = row * 128 + (((lane >> 4) ^ (row & 7)) * 16);
  }

  f32x4 acc[4][4];
#pragma unroll
  for (int m = 0; m < 4; ++m)
#pragma unroll
    for (int n = 0; n < 4; ++n) acc[m][n] = (f32x4){0.f, 0.f, 0.f, 0.f};

  const int NS = IDIM / 64;
  for (int s = 0; s < NS; ++s) {
    const int k0 = s * 64;
    __syncthreads();
#pragma unroll
    for (int p = 0; p < 4; ++p) {
      __builtin_amdgcn_global_load_lds(
          (const __attribute__((address_space(1))) void*)(gA[p] + k0),
          (__attribute__((address_space(3))) void*)((char*)Al + (p * 256 + tid) * 16), 16, 0, 0);
      __builtin_amdgcn_global_load_lds(
          (const __attribute__((address_space(1))) void*)(gB[p] + k0),
          (__attribute__((address_space(3))) void*)((char*)Bl + (p * 256 + tid) * 16), 16, 0, 0);
    }
    __syncthreads();
#pragma unroll
    for (int kk = 0; kk < 2; ++kk) {
      short8 a[4], b[4];
#pragma unroll
      for (int m = 0; m < 4; ++m) a[m] = *(const short8*)((const char*)Al + (aaddr[m] ^ (kk * 64)));
#pragma unroll
      for (int n = 0; n < 4; ++n) b[n] = *(const short8*)((const char*)Bl + (baddr[n] ^ (kk * 64)));
#pragma unroll
      for (int m = 0; m < 4; ++m)
#pragma unroll
        for (int n = 0; n < 4; ++n)
          acc[m][n] = __builtin_amdgcn_mfma_f32_16x16x32_bf16(a[m], b[n], acc[m][n], 0, 0, 0);
    }
  }

  // epilogue: scale by gate, bf16 store into pair rows (pads have gate 0)
#pragma unroll
  for (int m = 0; m < 4; ++m) {
    const int lr = wr * 64 + m * 16 + (lane >> 4) * 4;
#pragma unroll
    for (int n = 0; n < 4; ++n) {
      const int col = hcol0 + wc * 64 + n * 16 + (lane & 15);
#pragma unroll
      for (int r = 0; r < 4; ++r) {
        const float g = s_g[lr + r];
        pair[(size_t)(row0 + lr + r) * HDIM + col] = f32_to_bf16(g * acc[m][n][r]);
      }
    }
  }
}

// ---------------- combine: out[t] = pair[inv[t,0]] + pair[inv[t,1]] ----------------
__global__ void combine_kernel(const unsigned short* __restrict__ pair,
                               const int* __restrict__ inv, float* __restrict__ out) {
  const int gid = blockIdx.x * 256 + threadIdx.x;     // NUM_T*HDIM/8 threads
  const int t = gid >> 7;
  const int c8 = (gid & 127) << 3;
  const short8 v0 = *(const short8*)(pair + (size_t)inv[t * 2] * HDIM + c8);
  const short8 v1 = *(const short8*)(pair + (size_t)inv[t * 2 + 1] * HDIM + c8);
  float o[8];
#pragma unroll
  for (int j = 0; j < 8; ++j)
    o[j] = bf16_to_f32((unsigned short)v0[j]) + bf16_to_f32((unsigned short)v1[j]);
  float* dst = out + (size_t)t * HDIM + c8;
  ((float4*)dst)[0] = (float4){o[0], o[1], o[2], o[3]};
  ((float4*)dst)[1] = (float4){o[4], o[5], o[6], o[7]};
}

extern "C" void kernel_launch(void* const* d_in, const int* in_sizes, int n_in,
                              void* d_out, int out_size, void* d_ws, size_t ws_size,
                              hipStream_t stream) {
  const float* x   = (const float*)d_in[0];
  const float* wg  = (const float*)d_in[1];
  const float* wfc = (const float*)d_in[2];
  const float* wpj = (const float*)d_in[3];
  float* out    = (float*)d_out;
  float* logits = out + (size_t)NUM_T * HDIM;

  char* p = (char*)d_ws;
  auto alloc = [&](size_t bytes) { char* q = p; p += (bytes + 255) & ~size_t(255); return q; };
  unsigned short* xb    = (unsigned short*)alloc((size_t)NUM_T * HDIM * 2);
  unsigned short* wfcb  = (unsigned short*)alloc((size_t)NEXP * IDIM * HDIM * 2);
  unsigned short* wpb   = (unsigned short*)alloc((size_t)NEXP * HDIM * IDIM * 2);
  unsigned short* act   = (unsigned short*)alloc((size_t)MAXROWS * IDIM * 2);
  unsigned short* pair  = (unsigned short*)alloc((size_t)MAXROWS * HDIM * 2);
  int*            ptok  = (int*)alloc((size_t)MAXROWS * 4);
  float*          pgate = (float*)alloc((size_t)MAXROWS * 4);
  int*            tki   = (int*)alloc((size_t)NUM_T * 2 * 4);
  float*          tkg   = (float*)alloc((size_t)NUM_T * 2 * 4);
  int*            inv   = (int*)alloc((size_t)NUM_T * 2 * 4);
  int*            counts= (int*)alloc(64);
  int*            fill  = (int*)alloc(64);
  int*            off   = (int*)alloc(64);
  const size_t need = (size_t)(p - (char*)d_ws);
  if (need > ws_size) {
    fprintf(stderr, "kernel_launch: ws too small: need %zu have %zu\n", need, ws_size);
    hipMemsetAsync(d_out, 0, (size_t)out_size * 4, stream);
    return;
  }

  // zero aux region (pads -> token 0 / gate 0; counts/fill for atomics)
  hipMemsetAsync(ptok, 0, (size_t)(p - (char*)ptok), stream);

  const int n4w = NEXP * IDIM * HDIM / 4;
  cvt2_kernel<<<4096, 256, 0, stream>>>(wfc, wfcb, n4w, wpj, wpb, 2 * n4w);

  router_kernel<<<NUM_T / TPB, 256, 0, stream>>>(x, wg, logits, tki, tkg, counts, xb);
  offsets_kernel<<<1, 64, 0, stream>>>(counts, off);
  scatter_kernel<<<NUM_T / 256, 256, 0, stream>>>(tki, tkg, off, fill, ptok, pgate, inv);

  fc_gemm<<<(IDIM / 128) * RB, 256, 0, stream>>>(xb, wfcb, ptok, off, act);
  proj_gemm<<<(HDIM / 128) * RB, 256, 0, stream>>>(act, wpb, pgate, off, pair);
  combine_kernel<<<NUM_T * HDIM / 8 / 256, 256, 0, stream>>>(pair, inv, out);
}

// Round 11
// 545.116 us; speedup vs baseline: 1.7231x; 1.0156x over previous
//
#include <hip/hip_runtime.h>
#include <hip/hip_bf16.h>
#include <cstdint>
#include <cstdio>

#define NUM_T   8192
#define HDIM    1024
#define IDIM    4096
#define NEXP    8

#define ALGN    128                 // expert group alignment (= tile M)
#define RB      136                 // ceil((16384 + 8*127)/128)
#define MAXROWS (RB * 128)          // 17408 padded pair-rows
#define TPB     16                  // router tokens per block

typedef __attribute__((ext_vector_type(8))) short short8;
typedef __attribute__((ext_vector_type(4))) float f32x4;

__device__ __forceinline__ unsigned short f32_to_bf16(float f) {
  uint32_t u = __float_as_uint(f);
  u += 0x7fffu + ((u >> 16) & 1u);   // RNE; inputs are finite
  return (unsigned short)(u >> 16);
}
__device__ __forceinline__ float bf16_to_f32(unsigned short u) {
  return __uint_as_float(((uint32_t)u) << 16);
}
// bijective XCD swizzle: launch-order bid -> logical wgid, 8 contiguous chunks
__device__ __forceinline__ int xcd_swz(int bid, int nwg) {
  const int q = nwg >> 3, r = nwg & 7;
  const int x = bid & 7, i = bid >> 3;
  return (x < r ? x * (q + 1) : r * (q + 1) + (x - r) * q) + i;
}

// ---------------- fp32 -> bf16 convert, both weight tensors in one launch ----------------
__global__ void cvt2_kernel(const float* __restrict__ in0, unsigned short* __restrict__ out0,
                            int n4_0,
                            const float* __restrict__ in1, unsigned short* __restrict__ out1,
                            int n4_total) {
  int i = blockIdx.x * blockDim.x + threadIdx.x;
  const int stride = gridDim.x * blockDim.x;
  for (; i < n4_total; i += stride) {
    const float* in  = (i < n4_0) ? in0  : in1;
    unsigned short* out = (i < n4_0) ? out0 : out1;
    const int j = (i < n4_0) ? i : i - n4_0;
    const float4 v = ((const float4*)in)[j];
    ushort4 o;
    o.x = f32_to_bf16(v.x); o.y = f32_to_bf16(v.y);
    o.z = f32_to_bf16(v.z); o.w = f32_to_bf16(v.w);
    ((ushort4*)out)[j] = o;
  }
}

// ---------------- router: float4 loads, 4 tokens/wave, block-reduced counts ----------------
__global__ void router_kernel(const float* __restrict__ x, const float* __restrict__ wg,
                              float* __restrict__ logits, int* __restrict__ tki,
                              float* __restrict__ tkg, int* __restrict__ counts,
                              unsigned short* __restrict__ xb) {
  __shared__ int s_cnt[NEXP];
  const int tid = threadIdx.x;
  if (tid < NEXP) s_cnt[tid] = 0;
  __syncthreads();

  const int wave = tid >> 6;
  const int lane = tid & 63;

#pragma unroll 1
  for (int k = 0; k < 4; ++k) {
    const int t = blockIdx.x * TPB + wave * 4 + k;
    const float* xr = x + (size_t)t * HDIM;
    unsigned short* xbr = xb + (size_t)t * HDIM;

    float acc[NEXP];
#pragma unroll
    for (int e = 0; e < NEXP; ++e) acc[e] = 0.f;

#pragma unroll
    for (int it = 0; it < 4; ++it) {
      const int off = it * 256 + lane * 4;
      const float4 xv = *(const float4*)(xr + off);
      ushort4 o;
      o.x = f32_to_bf16(xv.x); o.y = f32_to_bf16(xv.y);
      o.z = f32_to_bf16(xv.z); o.w = f32_to_bf16(xv.w);
      *(ushort4*)(xbr + off) = o;
#pragma unroll
      for (int e = 0; e < NEXP; ++e) {
        const float4 wv = *(const float4*)(wg + e * HDIM + off);
        acc[e] += xv.x * wv.x + xv.y * wv.y + xv.z * wv.z + xv.w * wv.w;
      }
    }
#pragma unroll
    for (int e = 0; e < NEXP; ++e) {
#pragma unroll
      for (int s = 32; s > 0; s >>= 1) acc[e] += __shfl_xor(acc[e], s, 64);
    }
    if (lane == 0) {
      float v0 = -1e30f, v1 = -1e30f; int i0 = 0, i1 = 0;
#pragma unroll
      for (int e = 0; e < NEXP; ++e) {
        const float v = acc[e];
        logits[(size_t)t * NEXP + e] = v;
        if (v > v0)      { v1 = v0; i1 = i0; v0 = v; i0 = e; }
        else if (v > v1) { v1 = v; i1 = e; }
      }
      const float g0 = 1.f / (1.f + expf(v1 - v0));  // softmax over top-2
      tki[t * 2] = i0; tki[t * 2 + 1] = i1;
      tkg[t * 2] = g0; tkg[t * 2 + 1] = 1.f - g0;
      atomicAdd(&s_cnt[i0], 1);
      atomicAdd(&s_cnt[i1], 1);
    }
  }
  __syncthreads();
  if (tid < NEXP) atomicAdd(&counts[tid], s_cnt[tid]);
}

// ---------------- scatter: local prefix-sum of counts (identical in every block);
// block 0 publishes off[] for the GEMMs ----------------
__global__ void scatter_kernel(const int* __restrict__ tki, const float* __restrict__ tkg,
                               const int* __restrict__ counts, int* __restrict__ off_out,
                               int* __restrict__ fill,
                               int* __restrict__ ptok, float* __restrict__ pgate,
                               int* __restrict__ inv) {
  int o[NEXP + 1];
  o[0] = 0;
#pragma unroll
  for (int e = 0; e < NEXP; ++e) o[e + 1] = o[e] + ((counts[e] + ALGN - 1) & ~(ALGN - 1));
  if (blockIdx.x == 0 && threadIdx.x == 0) {
#pragma unroll
    for (int e = 0; e <= NEXP; ++e) off_out[e] = o[e];
  }
  const int t = blockIdx.x * 256 + threadIdx.x;
  if (t >= NUM_T) return;
#pragma unroll
  for (int k = 0; k < 2; ++k) {
    const int e = tki[t * 2 + k];
    const int pos = o[e] + atomicAdd(&fill[e], 1);
    ptok[pos] = t;
    pgate[pos] = tkg[t * 2 + k];
    inv[t * 2 + k] = pos;
  }
}

// =====================================================================
// fc GEMM: act = gelu(X[perm] @ Wfc[e]^T)
// m97-regime: 128x128 tile, 4 waves, BK=64, single-buffer 32 KB LDS,
// 2 barriers/K-step, plain C++ LDS reads, global_load_lds w16,
// XOR chunk swizzle, XCD chunk swizzle + 4x4 super-tile remap (L2 reuse:
// 4 A-panels + 4 B-panels = 2 MB working set < 4 MB XCD L2, each reused 4x).
// (256,4): 4 blocks/CU.
// =====================================================================
__launch_bounds__(256, 4)
__global__ void fc_gemm(const unsigned short* __restrict__ xb,
                        const unsigned short* __restrict__ wfcb,
                        const int* __restrict__ ptok,
                        const int* __restrict__ off,
                        unsigned short* __restrict__ act) {
  const int nwg = (IDIM / 128) * RB;           // 32 * 136 = 4352
  const int wgid = xcd_swz(blockIdx.x, nwg);
  // 4x4 super-tile remap: 16 wgids per ST; 8 col-groups x 34 row-groups
  const int st = wgid >> 4, w16 = wgid & 15;
  const int row0 = ((st >> 3) * 4 + (w16 >> 2)) * 128;
  const int icol0 = ((st & 7) * 4 + (w16 & 3)) * 128;
  if (row0 >= off[8]) return;
  int e = 0;
  while (row0 >= off[e + 1]) ++e;

  __shared__ __align__(16) unsigned short Al[128 * 64];
  __shared__ __align__(16) unsigned short Bl[128 * 64];
  __shared__ int s_tok[128];

  const int tid = threadIdx.x;
  if (tid < 128) s_tok[tid] = ptok[row0 + tid];
  __syncthreads();

  const unsigned short* gA[4];
  const unsigned short* gB[4];
#pragma unroll
  for (int p = 0; p < 4; ++p) {
    const int id = p * 256 + tid;
    const int r = id >> 3;
    const int cs = (id & 7) ^ (r & 7);
    gA[p] = xb + (size_t)s_tok[r] * HDIM + cs * 8;
    gB[p] = wfcb + ((size_t)e * IDIM + icol0 + r) * HDIM + cs * 8;
  }

  const int lane = tid & 63;
  const int wid = tid >> 6;
  const int wr = wid >> 1;
  const int wc = wid & 1;

  int aaddr[4], baddr[4];  // byte offsets (kk=0); kk=1 is ^64
#pragma unroll
  for (int m = 0; m < 4; ++m) {
    const int row = wr * 64 + m * 16 + (lane & 15);
    aaddr[m] = row * 128 + (((lane >> 4) ^ (row & 7)) * 16);
  }
#pragma unroll
  for (int n = 0; n < 4; ++n) {
    const int row = wc * 64 + n * 16 + (lane & 15);
    baddr[n] = row * 128 + (((lane >> 4) ^ (row & 7)) * 16);
  }

  f32x4 acc[4][4];
#pragma unroll
  for (int m = 0; m < 4; ++m)
#pragma unroll
    for (int n = 0; n < 4; ++n) acc[m][n] = (f32x4){0.f, 0.f, 0.f, 0.f};

  const int NS = HDIM / 64;
  for (int s = 0; s < NS; ++s) {
    const int k0 = s * 64;
    __syncthreads();               // prev step's reads done
#pragma unroll
    for (int p = 0; p < 4; ++p) {
      __builtin_amdgcn_global_load_lds(
          (const __attribute__((address_space(1))) void*)(gA[p] + k0),
          (__attribute__((address_space(3))) void*)((char*)Al + (p * 256 + tid) * 16), 16, 0, 0);
      __builtin_amdgcn_global_load_lds(
          (const __attribute__((address_space(1))) void*)(gB[p] + k0),
          (__attribute__((address_space(3))) void*)((char*)Bl + (p * 256 + tid) * 16), 16, 0, 0);
    }
    __syncthreads();               // stage landed (compiler drains vmcnt)
#pragma unroll
    for (int kk = 0; kk < 2; ++kk) {
      short8 a[4], b[4];
#pragma unroll
      for (int m = 0; m < 4; ++m) a[m] = *(const short8*)((const char*)Al + (aaddr[m] ^ (kk * 64)));
#pragma unroll
      for (int n = 0; n < 4; ++n) b[n] = *(const short8*)((const char*)Bl + (baddr[n] ^ (kk * 64)));
#pragma unroll
      for (int m = 0; m < 4; ++m)
#pragma unroll
        for (int n = 0; n < 4; ++n)
          acc[m][n] = __builtin_amdgcn_mfma_f32_16x16x32_bf16(a[m], b[n], acc[m][n], 0, 0, 0);
    }
  }

  // epilogue: exact gelu, bf16 store.  D: row=(lane>>4)*4+r, col=lane&15
#pragma unroll
  for (int m = 0; m < 4; ++m) {
    const int prow = row0 + wr * 64 + m * 16 + (lane >> 4) * 4;
#pragma unroll
    for (int n = 0; n < 4; ++n) {
      const int col = icol0 + wc * 64 + n * 16 + (lane & 15);
#pragma unroll
      for (int r = 0; r < 4; ++r) {
        const float v = acc[m][n][r];
        const float g = 0.5f * v * (1.0f + erff(v * 0.70710678118654752f));
        act[(size_t)(prow + r) * IDIM + col] = f32_to_bf16(g);
      }
    }
  }
}

// =====================================================================
// proj GEMM: pair[row] = gate * (act[row] @ Wproj[e]^T)
// Same m97-regime structure; 4x4 super-tile remap (2 col-groups x 34 row-groups).
// =====================================================================
__launch_bounds__(256, 4)
__global__ void proj_gemm(const unsigned short* __restrict__ actb,
                          const unsigned short* __restrict__ wpb,
                          const float* __restrict__ pgate,
                          const int* __restrict__ off,
                          unsigned short* __restrict__ pair) {
  const int nwg = (HDIM / 128) * RB;           // 8 * 136 = 1088
  const int wgid = xcd_swz(blockIdx.x, nwg);
  const int st = wgid >> 4, w16 = wgid & 15;
  const int row0 = ((st >> 1) * 4 + (w16 >> 2)) * 128;
  const int hcol0 = ((st & 1) * 4 + (w16 & 3)) * 128;
  if (row0 >= off[8]) return;
  int e = 0;
  while (row0 >= off[e + 1]) ++e;

  __shared__ __align__(16) unsigned short Al[128 * 64];
  __shared__ __align__(16) unsigned short Bl[128 * 64];
  __shared__ float s_g[128];

  const int tid = threadIdx.x;
  if (tid < 128) s_g[tid] = pgate[row0 + tid];
  __syncthreads();

  const unsigned short* gA[4];
  const unsigned short* gB[4];
#pragma unroll
  for (int p = 0; p < 4; ++p) {
    const int id = p * 256 + tid;
    const int r = id >> 3;
    const int cs = (id & 7) ^ (r & 7);
    gA[p] = actb + (size_t)(row0 + r) * IDIM + cs * 8;
    gB[p] = wpb + ((size_t)e * HDIM + hcol0 + r) * IDIM + cs * 8;
  }

  const int lane = tid & 63;
  const int wid = tid >> 6;
  const int wr = wid >> 1;
  const int wc = wid & 1;

  int aaddr[4], baddr[4];
#pragma unroll
  for (int m = 0; m < 4; ++m) {
    const int row = wr * 64 + m * 16 + (lane & 15);
    aaddr[m] = row * 128 + (((lane >> 4) ^ (row & 7)) * 16);
  }
#pragma unroll
  for (int n = 0; n < 4; ++n) {
    const int row = wc * 64 + n * 16 + (lane & 15);
    baddr[n] = row * 128 + (((lane >> 4) ^ (row & 7)) * 16);
  }

  f32x4 acc[4][4];
#pragma unroll
  for (int m = 0; m < 4; ++m)
#pragma unroll
    for (int n = 0; n < 4; ++n) acc[m][n] = (f32x4){0.f, 0.f, 0.f, 0.f};

  const int NS = IDIM / 64;
  for (int s = 0; s < NS; ++s) {
    const int k0 = s * 64;
    __syncthreads();
#pragma unroll
    for (int p = 0; p < 4; ++p) {
      __builtin_amdgcn_global_load_lds(
          (const __attribute__((address_space(1))) void*)(gA[p] + k0),
          (__attribute__((address_space(3))) void*)((char*)Al + (p * 256 + tid) * 16), 16, 0, 0);
      __builtin_amdgcn_global_load_lds(
          (const __attribute__((address_space(1))) void*)(gB[p] + k0),
          (__attribute__((address_space(3))) void*)((char*)Bl + (p * 256 + tid) * 16), 16, 0, 0);
    }
    __syncthreads();
#pragma unroll
    for (int kk = 0; kk < 2; ++kk) {
      short8 a[4], b[4];
#pragma unroll
      for (int m = 0; m < 4; ++m) a[m] = *(const short8*)((const char*)Al + (aaddr[m] ^ (kk * 64)));
#pragma unroll
      for (int n = 0; n < 4; ++n) b[n] = *(const short8*)((const char*)Bl + (baddr[n] ^ (kk * 64)));
#pragma unroll
      for (int m = 0; m < 4; ++m)
#pragma unroll
        for (int n = 0; n < 4; ++n)
          acc[m][n] = __builtin_amdgcn_mfma_f32_16x16x32_bf16(a[m], b[n], acc[m][n], 0, 0, 0);
    }
  }

  // epilogue: scale by gate, bf16 store into pair rows (pads have gate 0)
#pragma unroll
  for (int m = 0; m < 4; ++m) {
    const int lr = wr * 64 + m * 16 + (lane >> 4) * 4;
#pragma unroll
    for (int n = 0; n < 4; ++n) {
      const int col = hcol0 + wc * 64 + n * 16 + (lane & 15);
#pragma unroll
      for (int r = 0; r < 4; ++r) {
        const float g = s_g[lr + r];
        pair[(size_t)(row0 + lr + r) * HDIM + col] = f32_to_bf16(g * acc[m][n][r]);
      }
    }
  }
}

// ---------------- combine: out[t] = pair[inv[t,0]] + pair[inv[t,1]] ----------------
__global__ void combine_kernel(const unsigned short* __restrict__ pair,
                               const int* __restrict__ inv, float* __restrict__ out) {
  const int gid = blockIdx.x * 256 + threadIdx.x;     // NUM_T*HDIM/8 threads
  const int t = gid >> 7;
  const int c8 = (gid & 127) << 3;
  const short8 v0 = *(const short8*)(pair + (size_t)inv[t * 2] * HDIM + c8);
  const short8 v1 = *(const short8*)(pair + (size_t)inv[t * 2 + 1] * HDIM + c8);
  float o[8];
#pragma unroll
  for (int j = 0; j < 8; ++j)
    o[j] = bf16_to_f32((unsigned short)v0[j]) + bf16_to_f32((unsigned short)v1[j]);
  float* dst = out + (size_t)t * HDIM + c8;
  ((float4*)dst)[0] = (float4){o[0], o[1], o[2], o[3]};
  ((float4*)dst)[1] = (float4){o[4], o[5], o[6], o[7]};
}

extern "C" void kernel_launch(void* const* d_in, const int* in_sizes, int n_in,
                              void* d_out, int out_size, void* d_ws, size_t ws_size,
                              hipStream_t stream) {
  const float* x   = (const float*)d_in[0];
  const float* wg  = (const float*)d_in[1];
  const float* wfc = (const float*)d_in[2];
  const float* wpj = (const float*)d_in[3];
  float* out    = (float*)d_out;
  float* logits = out + (size_t)NUM_T * HDIM;

  char* p = (char*)d_ws;
  auto alloc = [&](size_t bytes) { char* q = p; p += (bytes + 255) & ~size_t(255); return q; };
  unsigned short* xb    = (unsigned short*)alloc((size_t)NUM_T * HDIM * 2);
  unsigned short* wfcb  = (unsigned short*)alloc((size_t)NEXP * IDIM * HDIM * 2);
  unsigned short* wpb   = (unsigned short*)alloc((size_t)NEXP * HDIM * IDIM * 2);
  unsigned short* act   = (unsigned short*)alloc((size_t)MAXROWS * IDIM * 2);
  unsigned short* pair  = (unsigned short*)alloc((size_t)MAXROWS * HDIM * 2);
  int*            ptok  = (int*)alloc((size_t)MAXROWS * 4);
  float*          pgate = (float*)alloc((size_t)MAXROWS * 4);
  int*            tki   = (int*)alloc((size_t)NUM_T * 2 * 4);
  float*          tkg   = (float*)alloc((size_t)NUM_T * 2 * 4);
  int*            inv   = (int*)alloc((size_t)NUM_T * 2 * 4);
  int*            counts= (int*)alloc(64);
  int*            fill  = (int*)alloc(64);
  int*            off   = (int*)alloc(64);
  const size_t need = (size_t)(p - (char*)d_ws);
  if (need > ws_size) {
    fprintf(stderr, "kernel_launch: ws too small: need %zu have %zu\n", need, ws_size);
    hipMemsetAsync(d_out, 0, (size_t)out_size * 4, stream);
    return;
  }

  // zero aux region (pads -> token 0 / gate 0; counts/fill for atomics)
  hipMemsetAsync(ptok, 0, (size_t)(p - (char*)ptok), stream);

  const int n4w = NEXP * IDIM * HDIM / 4;
  cvt2_kernel<<<4096, 256, 0, stream>>>(wfc, wfcb, n4w, wpj, wpb, 2 * n4w);

  router_kernel<<<NUM_T / TPB, 256, 0, stream>>>(x, wg, logits, tki, tkg, counts, xb);
  scatter_kernel<<<NUM_T / 256, 256, 0, stream>>>(tki, tkg, counts, off, fill, ptok, pgate, inv);

  fc_gemm<<<(IDIM / 128) * RB, 256, 0, stream>>>(xb, wfcb, ptok, off, act);
  proj_gemm<<<(HDIM / 128) * RB, 256, 0, stream>>>(act, wpb, pgate, off, pair);
  combine_kernel<<<NUM_T * HDIM / 8 / 256, 256, 0, stream>>>(pair, inv, out);
}